// Round 1
// baseline (3009.491 us; speedup 1.0000x reference)
//
#include <hip/hip_runtime.h>
#include <hip/hip_bf16.h>

#define DD 128
#define BN_EPS 1e-5f

// ---------------------------------------------------------------- utilities
__global__ __launch_bounds__(256) void zero_kernel(float* __restrict__ p, int n) {
    int i = blockIdx.x * 256 + threadIdx.x;
    if (i < n) p[i] = 0.f;
}

// ---------------------------------------------------------------- fused GEMM
// support = h @ W ; outb = h @ W_self + b
// tile: 32 rows x 128 cols, 256 threads, each thread 4 rows x 4 cols x 2 mats
__global__ __launch_bounds__(256) void gemm_fused(
    const float* __restrict__ h, const float* __restrict__ W,
    const float* __restrict__ Wself, const float* __restrict__ bias,
    float* __restrict__ support, float* __restrict__ outb, int N)
{
    __shared__ float Ast[32][32];   // [k][row] transposed A tile
    __shared__ float Ws[32][128];   // [k][col]
    __shared__ float Wss[32][128];

    const int t  = threadIdx.x;
    const int tx = t & 31;          // col group (4 cols each)
    const int ty = t >> 5;          // row group (4 rows each)
    const int r0 = blockIdx.x * 32;

    float acc1[4][4] = {{0.f}};
    float acc2[4][4] = {{0.f}};

    for (int k0 = 0; k0 < DD; k0 += 32) {
        // stage A tile transposed: thread -> (row = t>>3, k quad = (t&7)*4)
        {
            int row = t >> 3;
            int kq  = (t & 7) * 4;
            float4 a = make_float4(0.f, 0.f, 0.f, 0.f);
            int gr = r0 + row;
            if (gr < N) a = *(const float4*)&h[(size_t)gr * DD + k0 + kq];
            Ast[kq + 0][row] = a.x;
            Ast[kq + 1][row] = a.y;
            Ast[kq + 2][row] = a.z;
            Ast[kq + 3][row] = a.w;
        }
        // stage W chunks (32x128 each): 1024 float4s over 256 threads
        #pragma unroll
        for (int i = 0; i < 4; i++) {
            int idx = t + i * 256;
            int kk  = idx >> 5;
            int cc  = (idx & 31) * 4;
            *(float4*)&Ws[kk][cc]  = *(const float4*)&W[(size_t)(k0 + kk) * DD + cc];
            *(float4*)&Wss[kk][cc] = *(const float4*)&Wself[(size_t)(k0 + kk) * DD + cc];
        }
        __syncthreads();

        #pragma unroll
        for (int k = 0; k < 32; k++) {
            float4 a  = *(float4*)&Ast[k][ty * 4];
            float4 w1 = *(float4*)&Ws[k][tx * 4];
            float4 w2 = *(float4*)&Wss[k][tx * 4];
            float ar[4]  = {a.x, a.y, a.z, a.w};
            float w1r[4] = {w1.x, w1.y, w1.z, w1.w};
            float w2r[4] = {w2.x, w2.y, w2.z, w2.w};
            #pragma unroll
            for (int r = 0; r < 4; r++)
                #pragma unroll
                for (int c = 0; c < 4; c++) {
                    acc1[r][c] += ar[r] * w1r[c];
                    acc2[r][c] += ar[r] * w2r[c];
                }
        }
        __syncthreads();
    }

    const int col0 = tx * 4;
    float4 bv = *(const float4*)&bias[col0];
    #pragma unroll
    for (int r = 0; r < 4; r++) {
        int gr = r0 + ty * 4 + r;
        if (gr < N) {
            float4 s = make_float4(acc1[r][0], acc1[r][1], acc1[r][2], acc1[r][3]);
            *(float4*)&support[(size_t)gr * DD + col0] = s;
            float4 o = make_float4(acc2[r][0] + bv.x, acc2[r][1] + bv.y,
                                   acc2[r][2] + bv.z, acc2[r][3] + bv.w);
            *(float4*)&outb[(size_t)gr * DD + col0] = o;
        }
    }
}

// ---------------------------------------------------------------- SpMM scatter
// outb[row[e]] += val[e] * support[col[e]]   (atomic)
__global__ __launch_bounds__(256) void spmm_scatter(
    const int* __restrict__ arow, const int* __restrict__ acol,
    const float* __restrict__ aval, const float* __restrict__ support,
    float* __restrict__ outb, int E)
{
    int idx = blockIdx.x * 256 + threadIdx.x;   // one per (edge, dim-quad)
    int total = E * 32;
    if (idx >= total) return;
    int e  = idx >> 5;
    int d4 = (idx & 31) << 2;
    int c = acol[e];
    int r = arow[e];
    float v = aval[e];
    float4 s = *(const float4*)&support[(size_t)c * DD + d4];
    float* p = &outb[(size_t)r * DD + d4];
    atomicAdd(p + 0, v * s.x);
    atomicAdd(p + 1, v * s.y);
    atomicAdd(p + 2, v * s.z);
    atomicAdd(p + 3, v * s.w);
}

// ---------------------------------------------------------------- BN stats
__global__ __launch_bounds__(256) void bn_stats(
    const float* __restrict__ outb, float* __restrict__ stats, int N)
{
    int c    = threadIdx.x & 127;
    int half = threadIdx.x >> 7;
    float s = 0.f, sq = 0.f;
    for (int r = blockIdx.x * 2 + half; r < N; r += gridDim.x * 2) {
        float v = outb[(size_t)r * DD + c];
        s += v; sq += v * v;
    }
    __shared__ float red[2][2][128];
    red[0][half][c] = s;
    red[1][half][c] = sq;
    __syncthreads();
    if (half == 0) {
        atomicAdd(&stats[c],       red[0][0][c] + red[0][1][c]);
        atomicAdd(&stats[128 + c], red[1][0][c] + red[1][1][c]);
    }
}

// ---------------------------------------------------------------- BN apply + ReLU (+x)
__global__ __launch_bounds__(256) void bn_apply(
    const float* __restrict__ outb, const float* __restrict__ stats,
    const float* __restrict__ gamma, const float* __restrict__ beta,
    const float* __restrict__ x, float* __restrict__ hout, int N, int addx)
{
    int idx = blockIdx.x * 256 + threadIdx.x;   // one per 4 elements
    int total = N * 32;
    if (idx >= total) return;
    int c4 = (idx & 31) * 4;
    float invN = 1.f / (float)N;
    float4 o = *(const float4*)&outb[(size_t)idx * 4];
    float4 res;
    float* rp = &res.x;
    const float* op = &o.x;
    #pragma unroll
    for (int j = 0; j < 4; j++) {
        int c = c4 + j;
        float mean = stats[c] * invN;
        float var  = stats[128 + c] * invN - mean * mean;
        float sc   = gamma[c] * rsqrtf(var + BN_EPS);
        float sh   = beta[c] - mean * sc;
        float v    = op[j] * sc + sh;
        rp[j] = v > 0.f ? v : 0.f;
    }
    if (addx) {
        float4 xv = *(const float4*)&x[(size_t)idx * 4];
        res.x += xv.x; res.y += xv.y; res.z += xv.z; res.w += xv.w;
    }
    *(float4*)&hout[(size_t)idx * 4] = res;
}

// ---------------------------------------------------------------- edge predictor
// one wave per edge: sigmoid(concat(emb[src],emb[dst]) . Wc + bc)
__global__ __launch_bounds__(256) void edge_pred(
    const float* __restrict__ emb, const int* __restrict__ ei,
    const float* __restrict__ Wc, const float* __restrict__ bc,
    float* __restrict__ outp, int Ep)
{
    int lane = threadIdx.x & 63;
    int wid  = (blockIdx.x * 256 + threadIdx.x) >> 6;
    int nw   = (gridDim.x * 256) >> 6;
    float w0 = Wc[lane];
    float w1 = Wc[lane + 64];
    float w2 = Wc[lane + 128];
    float w3 = Wc[lane + 192];
    float bias = bc[0];
    for (int e = wid; e < Ep; e += nw) {
        int src = ei[e];
        int dst = ei[Ep + e];
        const float* p1 = &emb[(size_t)src * DD];
        const float* p2 = &emb[(size_t)dst * DD];
        float acc = p1[lane] * w0 + p1[lane + 64] * w1
                  + p2[lane] * w2 + p2[lane + 64] * w3;
        #pragma unroll
        for (int off = 32; off > 0; off >>= 1)
            acc += __shfl_down(acc, off);
        if (lane == 0)
            outp[e] = 1.f / (1.f + expf(-(acc + bias)));
    }
}

// ---------------------------------------------------------------- launch
extern "C" void kernel_launch(void* const* d_in, const int* in_sizes, int n_in,
                              void* d_out, int out_size, void* d_ws, size_t ws_size,
                              hipStream_t stream) {
    const float* x        = (const float*)d_in[0];
    const int*   adj_row  = (const int*)  d_in[1];
    const int*   adj_col  = (const int*)  d_in[2];
    const float* adj_val  = (const float*)d_in[3];
    const int*   ei       = (const int*)  d_in[4];
    const float* W        = (const float*)d_in[5];
    const float* W_self   = (const float*)d_in[6];
    const float* b        = (const float*)d_in[7];
    const float* gamma    = (const float*)d_in[8];
    const float* beta     = (const float*)d_in[9];
    const float* Wc       = (const float*)d_in[10];
    const float* bc       = (const float*)d_in[11];
    float* outp = (float*)d_out;

    const int N  = in_sizes[0] / DD;    // 50000
    const int E  = in_sizes[1];         // 800000
    const int Ep = in_sizes[4] / 2;     // 500000

    size_t nd = (size_t)N * DD;
    float* support = (float*)d_ws;
    float* outb    = support + nd;
    float* hbuf    = outb + nd;
    float* stats   = hbuf + nd;         // 512 floats (2 layers x 256)

    // zero stats for both layers
    zero_kernel<<<2, 256, 0, stream>>>(stats, 512);

    const int gemm_grid  = (N + 31) / 32;
    const int spmm_grid  = (E * 32 + 255) / 256;
    const int bnap_grid  = (N * 32 + 255) / 256;

    for (int i = 0; i < 2; i++) {
        const float* hin = (i == 0) ? x : hbuf;
        gemm_fused<<<gemm_grid, 256, 0, stream>>>(
            hin, W + (size_t)i * DD * DD, W_self + (size_t)i * DD * DD,
            b + (size_t)i * DD, support, outb, N);
        spmm_scatter<<<spmm_grid, 256, 0, stream>>>(
            adj_row, adj_col, adj_val, support, outb, E);
        bn_stats<<<512, 256, 0, stream>>>(outb, stats + i * 256, N);
        bn_apply<<<bnap_grid, 256, 0, stream>>>(
            outb, stats + i * 256, gamma + (size_t)i * DD, beta + (size_t)i * DD,
            x, hbuf, N, i == 1 ? 1 : 0);
    }

    edge_pred<<<4096, 256, 0, stream>>>(hbuf, ei, Wc, bc, outp, Ep);
}

// Round 2
// 643.916 us; speedup vs baseline: 4.6737x; 4.6737x over previous
//
#include <hip/hip_runtime.h>
#include <hip/hip_bf16.h>

#define DD 128
#define BN_EPS 1e-5f

// ---------------------------------------------------------------- utilities
__global__ __launch_bounds__(256) void zero_int_kernel(int* __restrict__ p, int n) {
    int i = blockIdx.x * 256 + threadIdx.x;
    if (i < n) p[i] = 0;
}

// ---------------------------------------------------------------- CSR build
__global__ __launch_bounds__(256) void hist_kernel(
    const int* __restrict__ arow, int* __restrict__ counts, int E)
{
    int e = blockIdx.x * 256 + threadIdx.x;
    if (e < E) atomicAdd(&counts[arow[e]], 1);
}

// exclusive scan of counts[0..n) -> offs[0..n], cursor[0..n); offs[n]=total
__global__ __launch_bounds__(1024) void scan_kernel(
    const int* __restrict__ counts, int* __restrict__ offs,
    int* __restrict__ cursor, int n)
{
    __shared__ int sh[1024];
    const int tid = threadIdx.x;
    int carry = 0;
    const int nchunks = (n + 1023) / 1024;
    for (int ch = 0; ch < nchunks; ch++) {
        int i = ch * 1024 + tid;
        int v = (i < n) ? counts[i] : 0;
        sh[tid] = v;
        __syncthreads();
        #pragma unroll
        for (int off = 1; off < 1024; off <<= 1) {
            int t = (tid >= off) ? sh[tid - off] : 0;
            __syncthreads();
            sh[tid] += t;
            __syncthreads();
        }
        int excl = carry + sh[tid] - v;
        if (i < n) { offs[i] = excl; cursor[i] = excl; }
        carry += sh[1023];
        __syncthreads();
    }
    if (tid == 0) offs[n] = carry;
}

__global__ __launch_bounds__(256) void scatter_kernel(
    const int* __restrict__ arow, const int* __restrict__ acol,
    const float* __restrict__ aval, int* __restrict__ cursor,
    int* __restrict__ cols_s, float* __restrict__ vals_s, int E)
{
    int e = blockIdx.x * 256 + threadIdx.x;
    if (e >= E) return;
    int r = arow[e];
    int pos = atomicAdd(&cursor[r], 1);
    cols_s[pos] = acol[e];
    vals_s[pos] = aval[e];
}

// ---------------------------------------------------------------- fused GEMM
// support = h @ W ; outb = h @ W_self + b
__global__ __launch_bounds__(256) void gemm_fused(
    const float* __restrict__ h, const float* __restrict__ W,
    const float* __restrict__ Wself, const float* __restrict__ bias,
    float* __restrict__ support, float* __restrict__ outb, int N)
{
    __shared__ float Ast[32][32];   // [k][row] transposed A tile
    __shared__ float Ws[32][128];   // [k][col]
    __shared__ float Wss[32][128];

    const int t  = threadIdx.x;
    const int tx = t & 31;
    const int ty = t >> 5;
    const int r0 = blockIdx.x * 32;

    float acc1[4][4] = {{0.f}};
    float acc2[4][4] = {{0.f}};

    for (int k0 = 0; k0 < DD; k0 += 32) {
        {
            int row = t >> 3;
            int kq  = (t & 7) * 4;
            float4 a = make_float4(0.f, 0.f, 0.f, 0.f);
            int gr = r0 + row;
            if (gr < N) a = *(const float4*)&h[(size_t)gr * DD + k0 + kq];
            Ast[kq + 0][row] = a.x;
            Ast[kq + 1][row] = a.y;
            Ast[kq + 2][row] = a.z;
            Ast[kq + 3][row] = a.w;
        }
        #pragma unroll
        for (int i = 0; i < 4; i++) {
            int idx = t + i * 256;
            int kk  = idx >> 5;
            int cc  = (idx & 31) * 4;
            *(float4*)&Ws[kk][cc]  = *(const float4*)&W[(size_t)(k0 + kk) * DD + cc];
            *(float4*)&Wss[kk][cc] = *(const float4*)&Wself[(size_t)(k0 + kk) * DD + cc];
        }
        __syncthreads();

        #pragma unroll
        for (int k = 0; k < 32; k++) {
            float4 a  = *(float4*)&Ast[k][ty * 4];
            float4 w1 = *(float4*)&Ws[k][tx * 4];
            float4 w2 = *(float4*)&Wss[k][tx * 4];
            float ar[4]  = {a.x, a.y, a.z, a.w};
            float w1r[4] = {w1.x, w1.y, w1.z, w1.w};
            float w2r[4] = {w2.x, w2.y, w2.z, w2.w};
            #pragma unroll
            for (int r = 0; r < 4; r++)
                #pragma unroll
                for (int c = 0; c < 4; c++) {
                    acc1[r][c] += ar[r] * w1r[c];
                    acc2[r][c] += ar[r] * w2r[c];
                }
        }
        __syncthreads();
    }

    const int col0 = tx * 4;
    float4 bv = *(const float4*)&bias[col0];
    #pragma unroll
    for (int r = 0; r < 4; r++) {
        int gr = r0 + ty * 4 + r;
        if (gr < N) {
            float4 s = make_float4(acc1[r][0], acc1[r][1], acc1[r][2], acc1[r][3]);
            *(float4*)&support[(size_t)gr * DD + col0] = s;
            float4 o = make_float4(acc2[r][0] + bv.x, acc2[r][1] + bv.y,
                                   acc2[r][2] + bv.z, acc2[r][3] + bv.w);
            *(float4*)&outb[(size_t)gr * DD + col0] = o;
        }
    }
}

// ---------------------------------------------------------------- SpMM (CSR, no atomics)
// one wave per row: outb[row,:] += sum_e val[e] * support[col[e],:]
__global__ __launch_bounds__(256) void spmm_csr(
    const int* __restrict__ offs, const int* __restrict__ cols_s,
    const float* __restrict__ vals_s, const float* __restrict__ support,
    float* __restrict__ outb, int N)
{
    const int lane = threadIdx.x & 63;
    const int row  = (blockIdx.x * 256 + threadIdx.x) >> 6;
    if (row >= N) return;

    const int beg = offs[row];
    const int end = offs[row + 1];

    float2 acc = make_float2(0.f, 0.f);
    for (int base = beg; base < end; base += 64) {
        int n = end - base;
        if (n > 64) n = 64;
        int   cc = 0;
        float vv = 0.f;
        if (lane < n) {
            cc = cols_s[base + lane];
            vv = vals_s[base + lane];
        }
        for (int j = 0; j < n; j++) {
            int   c = __shfl(cc, j);
            float v = __shfl(vv, j);
            float2 s = *(const float2*)&support[((size_t)c << 7) + lane * 2];
            acc.x += v * s.x;
            acc.y += v * s.y;
        }
    }

    float2* op = (float2*)&outb[((size_t)row << 7) + lane * 2];
    float2 o = *op;
    o.x += acc.x;
    o.y += acc.y;
    *op = o;
}

// ---------------------------------------------------------------- BN stats
__global__ __launch_bounds__(256) void bn_stats(
    const float* __restrict__ outb, float* __restrict__ stats, int N)
{
    int c    = threadIdx.x & 127;
    int half = threadIdx.x >> 7;
    float s = 0.f, sq = 0.f;
    for (int r = blockIdx.x * 2 + half; r < N; r += gridDim.x * 2) {
        float v = outb[(size_t)r * DD + c];
        s += v; sq += v * v;
    }
    __shared__ float red[2][2][128];
    red[0][half][c] = s;
    red[1][half][c] = sq;
    __syncthreads();
    if (half == 0) {
        atomicAdd(&stats[c],       red[0][0][c] + red[0][1][c]);
        atomicAdd(&stats[128 + c], red[1][0][c] + red[1][1][c]);
    }
}

// ---------------------------------------------------------------- BN apply + ReLU (+x)
__global__ __launch_bounds__(256) void bn_apply(
    const float* __restrict__ outb, const float* __restrict__ stats,
    const float* __restrict__ gamma, const float* __restrict__ beta,
    const float* __restrict__ x, float* __restrict__ hout, int N, int addx)
{
    int idx = blockIdx.x * 256 + threadIdx.x;
    int total = N * 32;
    if (idx >= total) return;
    int c4 = (idx & 31) * 4;
    float invN = 1.f / (float)N;
    float4 o = *(const float4*)&outb[(size_t)idx * 4];
    float4 res;
    float* rp = &res.x;
    const float* op = &o.x;
    #pragma unroll
    for (int j = 0; j < 4; j++) {
        int c = c4 + j;
        float mean = stats[c] * invN;
        float var  = stats[128 + c] * invN - mean * mean;
        float sc   = gamma[c] * rsqrtf(var + BN_EPS);
        float sh   = beta[c] - mean * sc;
        float v    = op[j] * sc + sh;
        rp[j] = v > 0.f ? v : 0.f;
    }
    if (addx) {
        float4 xv = *(const float4*)&x[(size_t)idx * 4];
        res.x += xv.x; res.y += xv.y; res.z += xv.z; res.w += xv.w;
    }
    *(float4*)&hout[(size_t)idx * 4] = res;
}

// ---------------------------------------------------------------- edge predictor
__global__ __launch_bounds__(256) void edge_pred(
    const float* __restrict__ emb, const int* __restrict__ ei,
    const float* __restrict__ Wc, const float* __restrict__ bc,
    float* __restrict__ outp, int Ep)
{
    int lane = threadIdx.x & 63;
    int wid  = (blockIdx.x * 256 + threadIdx.x) >> 6;
    int nw   = (gridDim.x * 256) >> 6;
    float w0 = Wc[lane];
    float w1 = Wc[lane + 64];
    float w2 = Wc[lane + 128];
    float w3 = Wc[lane + 192];
    float bias = bc[0];
    for (int e = wid; e < Ep; e += nw) {
        int src = ei[e];
        int dst = ei[Ep + e];
        const float* p1 = &emb[(size_t)src * DD];
        const float* p2 = &emb[(size_t)dst * DD];
        float acc = p1[lane] * w0 + p1[lane + 64] * w1
                  + p2[lane] * w2 + p2[lane + 64] * w3;
        #pragma unroll
        for (int off = 32; off > 0; off >>= 1)
            acc += __shfl_down(acc, off);
        if (lane == 0)
            outp[e] = 1.f / (1.f + expf(-(acc + bias)));
    }
}

// ---------------------------------------------------------------- launch
extern "C" void kernel_launch(void* const* d_in, const int* in_sizes, int n_in,
                              void* d_out, int out_size, void* d_ws, size_t ws_size,
                              hipStream_t stream) {
    const float* x        = (const float*)d_in[0];
    const int*   adj_row  = (const int*)  d_in[1];
    const int*   adj_col  = (const int*)  d_in[2];
    const float* adj_val  = (const float*)d_in[3];
    const int*   ei       = (const int*)  d_in[4];
    const float* W        = (const float*)d_in[5];
    const float* W_self   = (const float*)d_in[6];
    const float* b        = (const float*)d_in[7];
    const float* gamma    = (const float*)d_in[8];
    const float* beta     = (const float*)d_in[9];
    const float* Wc       = (const float*)d_in[10];
    const float* bc       = (const float*)d_in[11];
    float* outp = (float*)d_out;

    const int N  = in_sizes[0] / DD;    // 50000
    const int E  = in_sizes[1];         // 800000
    const int Ep = in_sizes[4] / 2;     // 500000

    size_t nd = (size_t)N * DD;
    float* support = (float*)d_ws;
    float* outb    = support + nd;
    float* hbuf    = outb + nd;
    float* stats   = hbuf + nd;                 // 512 floats
    int*   counts  = (int*)(stats + 512);       // N
    int*   offs    = counts + N;                // N+1
    int*   cursor  = offs + N + 1;              // N
    int*   cols_s  = cursor + N;                // E
    float* vals_s  = (float*)(cols_s + E);      // E

    // ---- build CSR once per call ----
    zero_int_kernel<<<(N + 255) / 256, 256, 0, stream>>>(counts, N);
    zero_int_kernel<<<2, 256, 0, stream>>>((int*)stats, 512);  // fp32 zero == int zero
    hist_kernel<<<(E + 255) / 256, 256, 0, stream>>>(adj_row, counts, E);
    scan_kernel<<<1, 1024, 0, stream>>>(counts, offs, cursor, N);
    scatter_kernel<<<(E + 255) / 256, 256, 0, stream>>>(
        adj_row, adj_col, adj_val, cursor, cols_s, vals_s, E);

    const int gemm_grid = (N + 31) / 32;
    const int spmm_grid = (N * 64 + 255) / 256;   // one wave per row
    const int bnap_grid = (N * 32 + 255) / 256;

    for (int i = 0; i < 2; i++) {
        const float* hin = (i == 0) ? x : hbuf;
        gemm_fused<<<gemm_grid, 256, 0, stream>>>(
            hin, W + (size_t)i * DD * DD, W_self + (size_t)i * DD * DD,
            b + (size_t)i * DD, support, outb, N);
        spmm_csr<<<spmm_grid, 256, 0, stream>>>(
            offs, cols_s, vals_s, support, outb, N);
        bn_stats<<<512, 256, 0, stream>>>(outb, stats + i * 256, N);
        bn_apply<<<bnap_grid, 256, 0, stream>>>(
            outb, stats + i * 256, gamma + (size_t)i * DD, beta + (size_t)i * DD,
            x, hbuf, N, i == 1 ? 1 : 0);
    }

    edge_pred<<<4096, 256, 0, stream>>>(hbuf, ei, Wc, bc, outp, Ep);
}

// Round 3
// 558.513 us; speedup vs baseline: 5.3884x; 1.1529x over previous
//
#include <hip/hip_runtime.h>
#include <hip/hip_bf16.h>

#define DD 128
#define BN_EPS 1e-5f

// ---------------------------------------------------------------- utilities
__global__ __launch_bounds__(256) void zero_int_kernel(int* __restrict__ p, int n) {
    int i = blockIdx.x * 256 + threadIdx.x;
    if (i < n) p[i] = 0;
}

// ---------------------------------------------------------------- CSR build
__global__ __launch_bounds__(256) void hist_kernel(
    const int* __restrict__ arow, int* __restrict__ counts, int E)
{
    int e = blockIdx.x * 256 + threadIdx.x;
    if (e < E) atomicAdd(&counts[arow[e]], 1);
}

// phase 1: per-block (1024 counts) sums
__global__ __launch_bounds__(256) void block_sums(
    const int* __restrict__ counts, int* __restrict__ bsums, int n)
{
    int base = blockIdx.x * 1024 + threadIdx.x * 4;
    int s = 0;
    #pragma unroll
    for (int j = 0; j < 4; j++) { int i = base + j; if (i < n) s += counts[i]; }
    #pragma unroll
    for (int off = 1; off < 64; off <<= 1) s += __shfl_xor(s, off);
    __shared__ int ws[4];
    int lane = threadIdx.x & 63, w = threadIdx.x >> 6;
    if (lane == 0) ws[w] = s;
    __syncthreads();
    if (threadIdx.x == 0) bsums[blockIdx.x] = ws[0] + ws[1] + ws[2] + ws[3];
}

// phase 2: scan block sums in place (exclusive), write total to offs[n]
__global__ __launch_bounds__(1024) void scan_bsums(
    int* __restrict__ bsums, int nb, int* __restrict__ offs, int n)
{
    __shared__ int sh[1024];
    int tid = threadIdx.x;
    int v = (tid < nb) ? bsums[tid] : 0;
    sh[tid] = v;
    __syncthreads();
    for (int off = 1; off < 1024; off <<= 1) {
        int t = (tid >= off) ? sh[tid - off] : 0;
        __syncthreads();
        sh[tid] += t;
        __syncthreads();
    }
    if (tid < nb) bsums[tid] = sh[tid] - v;   // exclusive
    if (tid == 0) offs[n] = sh[1023];         // grand total
}

// phase 3: per-block exclusive scan + block offset -> offs, cursor
__global__ __launch_bounds__(256) void scan_final(
    const int* __restrict__ counts, const int* __restrict__ bsums,
    int* __restrict__ offs, int* __restrict__ cursor, int n)
{
    int tid  = threadIdx.x;
    int base = blockIdx.x * 1024 + tid * 4;
    int c[4]; int s = 0;
    #pragma unroll
    for (int j = 0; j < 4; j++) { int i = base + j; c[j] = (i < n) ? counts[i] : 0; s += c[j]; }
    int lane = tid & 63, w = tid >> 6;
    int inc = s;
    #pragma unroll
    for (int off = 1; off < 64; off <<= 1) {
        int t = __shfl_up(inc, off);
        if (lane >= off) inc += t;
    }
    __shared__ int ws[4];
    if (lane == 63) ws[w] = inc;
    __syncthreads();
    int woff = 0;
    for (int k = 0; k < w; k++) woff += ws[k];
    int excl = bsums[blockIdx.x] + woff + inc - s;
    #pragma unroll
    for (int j = 0; j < 4; j++) {
        int i = base + j;
        if (i < n) { offs[i] = excl; cursor[i] = excl; }
        excl += c[j];
    }
}

__global__ __launch_bounds__(256) void scatter_kernel(
    const int* __restrict__ arow, const int* __restrict__ acol,
    const float* __restrict__ aval, int* __restrict__ cursor,
    int* __restrict__ cols_s, float* __restrict__ vals_s, int E)
{
    int e = blockIdx.x * 256 + threadIdx.x;
    if (e >= E) return;
    int r = arow[e];
    int pos = atomicAdd(&cursor[r], 1);
    cols_s[pos] = acol[e];
    vals_s[pos] = aval[e];
}

// ---------------------------------------------------------------- fused GEMM
// support = h @ W ; outb = h @ W_self + b
__global__ __launch_bounds__(256) void gemm_fused(
    const float* __restrict__ h, const float* __restrict__ W,
    const float* __restrict__ Wself, const float* __restrict__ bias,
    float* __restrict__ support, float* __restrict__ outb, int N)
{
    __shared__ float Ast[32][32];
    __shared__ float Ws[32][128];
    __shared__ float Wss[32][128];

    const int t  = threadIdx.x;
    const int tx = t & 31;
    const int ty = t >> 5;
    const int r0 = blockIdx.x * 32;

    float acc1[4][4] = {{0.f}};
    float acc2[4][4] = {{0.f}};

    for (int k0 = 0; k0 < DD; k0 += 32) {
        {
            int row = t >> 3;
            int kq  = (t & 7) * 4;
            float4 a = make_float4(0.f, 0.f, 0.f, 0.f);
            int gr = r0 + row;
            if (gr < N) a = *(const float4*)&h[(size_t)gr * DD + k0 + kq];
            Ast[kq + 0][row] = a.x;
            Ast[kq + 1][row] = a.y;
            Ast[kq + 2][row] = a.z;
            Ast[kq + 3][row] = a.w;
        }
        #pragma unroll
        for (int i = 0; i < 4; i++) {
            int idx = t + i * 256;
            int kk  = idx >> 5;
            int cc  = (idx & 31) * 4;
            *(float4*)&Ws[kk][cc]  = *(const float4*)&W[(size_t)(k0 + kk) * DD + cc];
            *(float4*)&Wss[kk][cc] = *(const float4*)&Wself[(size_t)(k0 + kk) * DD + cc];
        }
        __syncthreads();

        #pragma unroll
        for (int k = 0; k < 32; k++) {
            float4 a  = *(float4*)&Ast[k][ty * 4];
            float4 w1 = *(float4*)&Ws[k][tx * 4];
            float4 w2 = *(float4*)&Wss[k][tx * 4];
            float ar[4]  = {a.x, a.y, a.z, a.w};
            float w1r[4] = {w1.x, w1.y, w1.z, w1.w};
            float w2r[4] = {w2.x, w2.y, w2.z, w2.w};
            #pragma unroll
            for (int r = 0; r < 4; r++)
                #pragma unroll
                for (int c = 0; c < 4; c++) {
                    acc1[r][c] += ar[r] * w1r[c];
                    acc2[r][c] += ar[r] * w2r[c];
                }
        }
        __syncthreads();
    }

    const int col0 = tx * 4;
    float4 bv = *(const float4*)&bias[col0];
    #pragma unroll
    for (int r = 0; r < 4; r++) {
        int gr = r0 + ty * 4 + r;
        if (gr < N) {
            float4 s = make_float4(acc1[r][0], acc1[r][1], acc1[r][2], acc1[r][3]);
            *(float4*)&support[(size_t)gr * DD + col0] = s;
            float4 o = make_float4(acc2[r][0] + bv.x, acc2[r][1] + bv.y,
                                   acc2[r][2] + bv.z, acc2[r][3] + bv.w);
            *(float4*)&outb[(size_t)gr * DD + col0] = o;
        }
    }
}

// ---------------------------------------------------------------- SpMM (CSR, no atomics)
__global__ __launch_bounds__(256) void spmm_csr(
    const int* __restrict__ offs, const int* __restrict__ cols_s,
    const float* __restrict__ vals_s, const float* __restrict__ support,
    float* __restrict__ outb, int N)
{
    const int lane = threadIdx.x & 63;
    const int row  = (blockIdx.x * 256 + threadIdx.x) >> 6;
    if (row >= N) return;

    const int beg = offs[row];
    const int end = offs[row + 1];

    float2 acc = make_float2(0.f, 0.f);
    for (int base = beg; base < end; base += 64) {
        int n = end - base;
        if (n > 64) n = 64;
        int   cc = 0;
        float vv = 0.f;
        if (lane < n) {
            cc = cols_s[base + lane];
            vv = vals_s[base + lane];
        }
        for (int j = 0; j < n; j++) {
            int   c = __shfl(cc, j);
            float v = __shfl(vv, j);
            float2 s = *(const float2*)&support[((size_t)c << 7) + lane * 2];
            acc.x += v * s.x;
            acc.y += v * s.y;
        }
    }

    float2* op = (float2*)&outb[((size_t)row << 7) + lane * 2];
    float2 o = *op;
    o.x += acc.x;
    o.y += acc.y;
    *op = o;
}

// ---------------------------------------------------------------- BN stats
__global__ __launch_bounds__(256) void bn_stats(
    const float* __restrict__ outb, float* __restrict__ stats, int N)
{
    int c    = threadIdx.x & 127;
    int half = threadIdx.x >> 7;
    float s = 0.f, sq = 0.f;
    for (int r = blockIdx.x * 2 + half; r < N; r += gridDim.x * 2) {
        float v = outb[(size_t)r * DD + c];
        s += v; sq += v * v;
    }
    __shared__ float red[2][2][128];
    red[0][half][c] = s;
    red[1][half][c] = sq;
    __syncthreads();
    if (half == 0) {
        atomicAdd(&stats[c],       red[0][0][c] + red[0][1][c]);
        atomicAdd(&stats[128 + c], red[1][0][c] + red[1][1][c]);
    }
}

// ---------------------------------------------------------------- BN apply + ReLU (+x)
__global__ __launch_bounds__(256) void bn_apply(
    const float* __restrict__ outb, const float* __restrict__ stats,
    const float* __restrict__ gamma, const float* __restrict__ beta,
    const float* __restrict__ x, float* __restrict__ hout, int N, int addx)
{
    int idx = blockIdx.x * 256 + threadIdx.x;
    int total = N * 32;
    if (idx >= total) return;
    int c4 = (idx & 31) * 4;
    float invN = 1.f / (float)N;
    float4 o = *(const float4*)&outb[(size_t)idx * 4];
    float4 res;
    float* rp = &res.x;
    const float* op = &o.x;
    #pragma unroll
    for (int j = 0; j < 4; j++) {
        int c = c4 + j;
        float mean = stats[c] * invN;
        float var  = stats[128 + c] * invN - mean * mean;
        float sc   = gamma[c] * rsqrtf(var + BN_EPS);
        float sh   = beta[c] - mean * sc;
        float v    = op[j] * sc + sh;
        rp[j] = v > 0.f ? v : 0.f;
    }
    if (addx) {
        float4 xv = *(const float4*)&x[(size_t)idx * 4];
        res.x += xv.x; res.y += xv.y; res.z += xv.z; res.w += xv.w;
    }
    *(float4*)&hout[(size_t)idx * 4] = res;
}

// ---------------------------------------------------------------- edge predictor
__global__ __launch_bounds__(256) void edge_pred(
    const float* __restrict__ emb, const int* __restrict__ ei,
    const float* __restrict__ Wc, const float* __restrict__ bc,
    float* __restrict__ outp, int Ep)
{
    int lane = threadIdx.x & 63;
    int wid  = (blockIdx.x * 256 + threadIdx.x) >> 6;
    int nw   = (gridDim.x * 256) >> 6;
    float w0 = Wc[lane];
    float w1 = Wc[lane + 64];
    float w2 = Wc[lane + 128];
    float w3 = Wc[lane + 192];
    float bias = bc[0];
    for (int e = wid; e < Ep; e += nw) {
        int src = ei[e];
        int dst = ei[Ep + e];
        const float* p1 = &emb[(size_t)src * DD];
        const float* p2 = &emb[(size_t)dst * DD];
        float acc = p1[lane] * w0 + p1[lane + 64] * w1
                  + p2[lane] * w2 + p2[lane + 64] * w3;
        #pragma unroll
        for (int off = 32; off > 0; off >>= 1)
            acc += __shfl_down(acc, off);
        if (lane == 0)
            outp[e] = 1.f / (1.f + expf(-(acc + bias)));
    }
}

// ---------------------------------------------------------------- launch
extern "C" void kernel_launch(void* const* d_in, const int* in_sizes, int n_in,
                              void* d_out, int out_size, void* d_ws, size_t ws_size,
                              hipStream_t stream) {
    const float* x        = (const float*)d_in[0];
    const int*   adj_row  = (const int*)  d_in[1];
    const int*   adj_col  = (const int*)  d_in[2];
    const float* adj_val  = (const float*)d_in[3];
    const int*   ei       = (const int*)  d_in[4];
    const float* W        = (const float*)d_in[5];
    const float* W_self   = (const float*)d_in[6];
    const float* b        = (const float*)d_in[7];
    const float* gamma    = (const float*)d_in[8];
    const float* beta     = (const float*)d_in[9];
    const float* Wc       = (const float*)d_in[10];
    const float* bc       = (const float*)d_in[11];
    float* outp = (float*)d_out;

    const int N  = in_sizes[0] / DD;    // 50000
    const int E  = in_sizes[1];         // 800000
    const int Ep = in_sizes[4] / 2;     // 500000

    size_t nd = (size_t)N * DD;
    float* support = (float*)d_ws;
    float* outb    = support + nd;
    float* hbuf    = outb + nd;
    float* stats   = hbuf + nd;                 // 512 floats
    int*   counts  = (int*)(stats + 512);       // N
    int*   offs    = counts + N;                // N+1
    int*   cursor  = offs + N + 1;              // N
    int*   cols_s  = cursor + N;                // E
    float* vals_s  = (float*)(cols_s + E);      // E
    int*   bsums   = (int*)(vals_s + E);        // <=1024

    const int nb = (N + 1023) / 1024;

    // ---- build CSR once per call ----
    zero_int_kernel<<<(N + 255) / 256, 256, 0, stream>>>(counts, N);
    zero_int_kernel<<<2, 256, 0, stream>>>((int*)stats, 512);
    hist_kernel<<<(E + 255) / 256, 256, 0, stream>>>(adj_row, counts, E);
    block_sums<<<nb, 256, 0, stream>>>(counts, bsums, N);
    scan_bsums<<<1, 1024, 0, stream>>>(bsums, nb, offs, N);
    scan_final<<<nb, 256, 0, stream>>>(counts, bsums, offs, cursor, N);
    scatter_kernel<<<(E + 255) / 256, 256, 0, stream>>>(
        adj_row, adj_col, adj_val, cursor, cols_s, vals_s, E);

    const int gemm_grid = (N + 31) / 32;
    const int spmm_grid = (N * 64 + 255) / 256;
    const int bnap_grid = (N * 32 + 255) / 256;

    for (int i = 0; i < 2; i++) {
        const float* hin = (i == 0) ? x : hbuf;
        gemm_fused<<<gemm_grid, 256, 0, stream>>>(
            hin, W + (size_t)i * DD * DD, W_self + (size_t)i * DD * DD,
            b + (size_t)i * DD, support, outb, N);
        spmm_csr<<<spmm_grid, 256, 0, stream>>>(
            offs, cols_s, vals_s, support, outb, N);
        bn_stats<<<512, 256, 0, stream>>>(outb, stats + i * 256, N);
        bn_apply<<<bnap_grid, 256, 0, stream>>>(
            outb, stats + i * 256, gamma + (size_t)i * DD, beta + (size_t)i * DD,
            x, hbuf, N, i == 1 ? 1 : 0);
    }

    edge_pred<<<4096, 256, 0, stream>>>(hbuf, ei, Wc, bc, outp, Ep);
}

// Round 4
// 488.869 us; speedup vs baseline: 6.1560x; 1.1425x over previous
//
#include <hip/hip_runtime.h>
#include <hip/hip_bf16.h>

#define DD 128
#define BN_EPS 1e-5f

// ---------------------------------------------------------------- utilities
__global__ __launch_bounds__(256) void zero_int_kernel(int* __restrict__ p, int n) {
    int i = blockIdx.x * 256 + threadIdx.x;
    if (i < n) p[i] = 0;
}

// ---------------------------------------------------------------- CSR build
__global__ __launch_bounds__(256) void hist_kernel(
    const int* __restrict__ arow, int* __restrict__ counts, int E)
{
    int e = blockIdx.x * 256 + threadIdx.x;
    if (e < E) atomicAdd(&counts[arow[e]], 1);
}

// phase 1: per-block (1024 counts) sums
__global__ __launch_bounds__(256) void block_sums(
    const int* __restrict__ counts, int* __restrict__ bsums, int n)
{
    int base = blockIdx.x * 1024 + threadIdx.x * 4;
    int s = 0;
    #pragma unroll
    for (int j = 0; j < 4; j++) { int i = base + j; if (i < n) s += counts[i]; }
    #pragma unroll
    for (int off = 1; off < 64; off <<= 1) s += __shfl_xor(s, off);
    __shared__ int ws[4];
    int lane = threadIdx.x & 63, w = threadIdx.x >> 6;
    if (lane == 0) ws[w] = s;
    __syncthreads();
    if (threadIdx.x == 0) bsums[blockIdx.x] = ws[0] + ws[1] + ws[2] + ws[3];
}

// phase 2: scan block sums in place (exclusive), write total to offs[n]
__global__ __launch_bounds__(1024) void scan_bsums(
    int* __restrict__ bsums, int nb, int* __restrict__ offs, int n)
{
    __shared__ int sh[1024];
    int tid = threadIdx.x;
    int v = (tid < nb) ? bsums[tid] : 0;
    sh[tid] = v;
    __syncthreads();
    for (int off = 1; off < 1024; off <<= 1) {
        int t = (tid >= off) ? sh[tid - off] : 0;
        __syncthreads();
        sh[tid] += t;
        __syncthreads();
    }
    if (tid < nb) bsums[tid] = sh[tid] - v;   // exclusive
    if (tid == 0) offs[n] = sh[1023];         // grand total
}

// phase 3: per-block exclusive scan + block offset -> offs, cursor
__global__ __launch_bounds__(256) void scan_final(
    const int* __restrict__ counts, const int* __restrict__ bsums,
    int* __restrict__ offs, int* __restrict__ cursor, int n)
{
    int tid  = threadIdx.x;
    int base = blockIdx.x * 1024 + tid * 4;
    int c[4]; int s = 0;
    #pragma unroll
    for (int j = 0; j < 4; j++) { int i = base + j; c[j] = (i < n) ? counts[i] : 0; s += c[j]; }
    int lane = tid & 63, w = tid >> 6;
    int inc = s;
    #pragma unroll
    for (int off = 1; off < 64; off <<= 1) {
        int t = __shfl_up(inc, off);
        if (lane >= off) inc += t;
    }
    __shared__ int ws[4];
    if (lane == 63) ws[w] = inc;
    __syncthreads();
    int woff = 0;
    for (int k = 0; k < w; k++) woff += ws[k];
    int excl = bsums[blockIdx.x] + woff + inc - s;
    #pragma unroll
    for (int j = 0; j < 4; j++) {
        int i = base + j;
        if (i < n) { offs[i] = excl; cursor[i] = excl; }
        excl += c[j];
    }
}

__global__ __launch_bounds__(256) void scatter_kernel(
    const int* __restrict__ arow, const int* __restrict__ acol,
    const float* __restrict__ aval, int* __restrict__ cursor,
    int* __restrict__ cols_s, float* __restrict__ vals_s, int E)
{
    int e = blockIdx.x * 256 + threadIdx.x;
    if (e >= E) return;
    int r = arow[e];
    int pos = atomicAdd(&cursor[r], 1);
    cols_s[pos] = acol[e];
    vals_s[pos] = aval[e];
}

// ---------------------------------------------------------------- fused GEMM
// support = h @ W ; outb = h @ W_self + b
__global__ __launch_bounds__(256) void gemm_fused(
    const float* __restrict__ h, const float* __restrict__ W,
    const float* __restrict__ Wself, const float* __restrict__ bias,
    float* __restrict__ support, float* __restrict__ outb, int N)
{
    __shared__ float Ast[32][32];
    __shared__ float Ws[32][128];
    __shared__ float Wss[32][128];

    const int t  = threadIdx.x;
    const int tx = t & 31;
    const int ty = t >> 5;
    const int r0 = blockIdx.x * 32;

    float acc1[4][4] = {{0.f}};
    float acc2[4][4] = {{0.f}};

    for (int k0 = 0; k0 < DD; k0 += 32) {
        {
            int row = t >> 3;
            int kq  = (t & 7) * 4;
            float4 a = make_float4(0.f, 0.f, 0.f, 0.f);
            int gr = r0 + row;
            if (gr < N) a = *(const float4*)&h[(size_t)gr * DD + k0 + kq];
            Ast[kq + 0][row] = a.x;
            Ast[kq + 1][row] = a.y;
            Ast[kq + 2][row] = a.z;
            Ast[kq + 3][row] = a.w;
        }
        #pragma unroll
        for (int i = 0; i < 4; i++) {
            int idx = t + i * 256;
            int kk  = idx >> 5;
            int cc  = (idx & 31) * 4;
            *(float4*)&Ws[kk][cc]  = *(const float4*)&W[(size_t)(k0 + kk) * DD + cc];
            *(float4*)&Wss[kk][cc] = *(const float4*)&Wself[(size_t)(k0 + kk) * DD + cc];
        }
        __syncthreads();

        #pragma unroll
        for (int k = 0; k < 32; k++) {
            float4 a  = *(float4*)&Ast[k][ty * 4];
            float4 w1 = *(float4*)&Ws[k][tx * 4];
            float4 w2 = *(float4*)&Wss[k][tx * 4];
            float ar[4]  = {a.x, a.y, a.z, a.w};
            float w1r[4] = {w1.x, w1.y, w1.z, w1.w};
            float w2r[4] = {w2.x, w2.y, w2.z, w2.w};
            #pragma unroll
            for (int r = 0; r < 4; r++)
                #pragma unroll
                for (int c = 0; c < 4; c++) {
                    acc1[r][c] += ar[r] * w1r[c];
                    acc2[r][c] += ar[r] * w2r[c];
                }
        }
        __syncthreads();
    }

    const int col0 = tx * 4;
    float4 bv = *(const float4*)&bias[col0];
    #pragma unroll
    for (int r = 0; r < 4; r++) {
        int gr = r0 + ty * 4 + r;
        if (gr < N) {
            float4 s = make_float4(acc1[r][0], acc1[r][1], acc1[r][2], acc1[r][3]);
            *(float4*)&support[(size_t)gr * DD + col0] = s;
            float4 o = make_float4(acc2[r][0] + bv.x, acc2[r][1] + bv.y,
                                   acc2[r][2] + bv.z, acc2[r][3] + bv.w);
            *(float4*)&outb[(size_t)gr * DD + col0] = o;
        }
    }
}

// ---------------------------------------------------------------- SpMM (CSR, no atomics)
__global__ __launch_bounds__(256) void spmm_csr(
    const int* __restrict__ offs, const int* __restrict__ cols_s,
    const float* __restrict__ vals_s, const float* __restrict__ support,
    float* __restrict__ outb, int N)
{
    const int lane = threadIdx.x & 63;
    const int row  = (blockIdx.x * 256 + threadIdx.x) >> 6;
    if (row >= N) return;

    const int beg = offs[row];
    const int end = offs[row + 1];

    float2 acc = make_float2(0.f, 0.f);
    for (int base = beg; base < end; base += 64) {
        int n = end - base;
        if (n > 64) n = 64;
        int   cc = 0;
        float vv = 0.f;
        if (lane < n) {
            cc = cols_s[base + lane];
            vv = vals_s[base + lane];
        }
        for (int j = 0; j < n; j++) {
            int   c = __shfl(cc, j);
            float v = __shfl(vv, j);
            float2 s = *(const float2*)&support[((size_t)c << 7) + lane * 2];
            acc.x += v * s.x;
            acc.y += v * s.y;
        }
    }

    float2* op = (float2*)&outb[((size_t)row << 7) + lane * 2];
    float2 o = *op;
    o.x += acc.x;
    o.y += acc.y;
    *op = o;
}

// ---------------------------------------------------------------- BN stats
__global__ __launch_bounds__(256) void bn_stats(
    const float* __restrict__ outb, float* __restrict__ stats, int N)
{
    int c    = threadIdx.x & 127;
    int half = threadIdx.x >> 7;
    float s = 0.f, sq = 0.f;
    for (int r = blockIdx.x * 2 + half; r < N; r += gridDim.x * 2) {
        float v = outb[(size_t)r * DD + c];
        s += v; sq += v * v;
    }
    __shared__ float red[2][2][128];
    red[0][half][c] = s;
    red[1][half][c] = sq;
    __syncthreads();
    if (half == 0) {
        atomicAdd(&stats[c],       red[0][0][c] + red[0][1][c]);
        atomicAdd(&stats[128 + c], red[1][0][c] + red[1][1][c]);
    }
}

// ---------------------------------------------------------------- BN apply + ReLU
// addx==0: hout = relu(bn(outb))
// addx==1: node_emb = relu(bn(outb)) + x; reduce per-row scores
//          s1[r] = node_emb[r,:]·Wc[0:128], s2[r] = node_emb[r,:]·Wc[128:256]
//          (hout not written — node_emb never materialized)
__global__ __launch_bounds__(256) void bn_apply(
    const float* __restrict__ outb, const float* __restrict__ stats,
    const float* __restrict__ gamma, const float* __restrict__ beta,
    const float* __restrict__ x, float* __restrict__ hout,
    float* __restrict__ s1, float* __restrict__ s2,
    const float* __restrict__ Wc, int N, int addx)
{
    int idx = blockIdx.x * 256 + threadIdx.x;
    int total = N * 32;
    if (idx >= total) return;
    int c4 = (idx & 31) * 4;
    float invN = 1.f / (float)N;
    float4 o = *(const float4*)&outb[(size_t)idx * 4];
    float4 res;
    float* rp = &res.x;
    const float* op = &o.x;
    #pragma unroll
    for (int j = 0; j < 4; j++) {
        int c = c4 + j;
        float mean = stats[c] * invN;
        float var  = stats[128 + c] * invN - mean * mean;
        float sc   = gamma[c] * rsqrtf(var + BN_EPS);
        float sh   = beta[c] - mean * sc;
        float v    = op[j] * sc + sh;
        rp[j] = v > 0.f ? v : 0.f;
    }
    if (!addx) {
        *(float4*)&hout[(size_t)idx * 4] = res;
    } else {
        float4 xv = *(const float4*)&x[(size_t)idx * 4];
        res.x += xv.x; res.y += xv.y; res.z += xv.z; res.w += xv.w;
        float4 w1 = *(const float4*)&Wc[c4];
        float4 w2 = *(const float4*)&Wc[128 + c4];
        float a1 = res.x * w1.x + res.y * w1.y + res.z * w1.z + res.w * w1.w;
        float a2 = res.x * w2.x + res.y * w2.y + res.z * w2.z + res.w * w2.w;
        #pragma unroll
        for (int off = 1; off < 32; off <<= 1) {
            a1 += __shfl_xor(a1, off);
            a2 += __shfl_xor(a2, off);
        }
        if ((idx & 31) == 0) {
            int row = idx >> 5;
            s1[row] = a1;
            s2[row] = a2;
        }
    }
}

// ---------------------------------------------------------------- edge predictor (scalar)
__global__ __launch_bounds__(256) void edge_pred_scalar(
    const float* __restrict__ s1, const float* __restrict__ s2,
    const int* __restrict__ ei, const float* __restrict__ bc,
    float* __restrict__ outp, int Ep)
{
    int e = blockIdx.x * 256 + threadIdx.x;
    if (e >= Ep) return;
    float v = s1[ei[e]] + s2[ei[Ep + e]] + bc[0];
    outp[e] = 1.f / (1.f + expf(-v));
}

// ---------------------------------------------------------------- launch
extern "C" void kernel_launch(void* const* d_in, const int* in_sizes, int n_in,
                              void* d_out, int out_size, void* d_ws, size_t ws_size,
                              hipStream_t stream) {
    const float* x        = (const float*)d_in[0];
    const int*   adj_row  = (const int*)  d_in[1];
    const int*   adj_col  = (const int*)  d_in[2];
    const float* adj_val  = (const float*)d_in[3];
    const int*   ei       = (const int*)  d_in[4];
    const float* W        = (const float*)d_in[5];
    const float* W_self   = (const float*)d_in[6];
    const float* b        = (const float*)d_in[7];
    const float* gamma    = (const float*)d_in[8];
    const float* beta     = (const float*)d_in[9];
    const float* Wc       = (const float*)d_in[10];
    const float* bc       = (const float*)d_in[11];
    float* outp = (float*)d_out;

    const int N  = in_sizes[0] / DD;    // 50000
    const int E  = in_sizes[1];         // 800000
    const int Ep = in_sizes[4] / 2;     // 500000

    size_t nd = (size_t)N * DD;
    float* support = (float*)d_ws;
    float* outb    = support + nd;
    float* hbuf    = outb + nd;
    float* stats   = hbuf + nd;                 // 512 floats
    int*   counts  = (int*)(stats + 512);       // N
    int*   offs    = counts + N;                // N+1
    int*   cursor  = offs + N + 1;              // N
    int*   cols_s  = cursor + N;                // E
    float* vals_s  = (float*)(cols_s + E);      // E
    int*   bsums   = (int*)(vals_s + E);        // <=1024
    float* s1      = (float*)(bsums + 1024);    // N
    float* s2      = s1 + N;                    // N

    const int nb = (N + 1023) / 1024;

    // ---- build CSR once per call ----
    zero_int_kernel<<<(N + 255) / 256, 256, 0, stream>>>(counts, N);
    zero_int_kernel<<<2, 256, 0, stream>>>((int*)stats, 512);
    hist_kernel<<<(E + 255) / 256, 256, 0, stream>>>(adj_row, counts, E);
    block_sums<<<nb, 256, 0, stream>>>(counts, bsums, N);
    scan_bsums<<<1, 1024, 0, stream>>>(bsums, nb, offs, N);
    scan_final<<<nb, 256, 0, stream>>>(counts, bsums, offs, cursor, N);
    scatter_kernel<<<(E + 255) / 256, 256, 0, stream>>>(
        adj_row, adj_col, adj_val, cursor, cols_s, vals_s, E);

    const int gemm_grid = (N + 31) / 32;
    const int spmm_grid = (N * 64 + 255) / 256;
    const int bnap_grid = (N * 32 + 255) / 256;

    for (int i = 0; i < 2; i++) {
        const float* hin = (i == 0) ? x : hbuf;
        gemm_fused<<<gemm_grid, 256, 0, stream>>>(
            hin, W + (size_t)i * DD * DD, W_self + (size_t)i * DD * DD,
            b + (size_t)i * DD, support, outb, N);
        spmm_csr<<<spmm_grid, 256, 0, stream>>>(
            offs, cols_s, vals_s, support, outb, N);
        bn_stats<<<512, 256, 0, stream>>>(outb, stats + i * 256, N);
        bn_apply<<<bnap_grid, 256, 0, stream>>>(
            outb, stats + i * 256, gamma + (size_t)i * DD, beta + (size_t)i * DD,
            x, hbuf, s1, s2, Wc, N, i == 1 ? 1 : 0);
    }

    edge_pred_scalar<<<(Ep + 255) / 256, 256, 0, stream>>>(s1, s2, ei, bc, outp, Ep);
}

// Round 5
// 423.235 us; speedup vs baseline: 7.1107x; 1.1551x over previous
//
#include <hip/hip_runtime.h>
#include <hip/hip_bf16.h>

#define DD 128
#define BN_EPS 1e-5f

static __device__ __forceinline__ unsigned short f2bf(float f) {
    __hip_bfloat16 h = __float2bfloat16(f);   // RNE
    return *reinterpret_cast<unsigned short*>(&h);
}
static __device__ __forceinline__ float bf2f(unsigned short u) {
    return __uint_as_float(((unsigned)u) << 16);
}

// ---------------------------------------------------------------- utilities
__global__ __launch_bounds__(256) void zero_int_kernel(int* __restrict__ p, int n) {
    int i = blockIdx.x * 256 + threadIdx.x;
    if (i < n) p[i] = 0;
}

// ---------------------------------------------------------------- CSR build
__global__ __launch_bounds__(256) void hist_kernel(
    const int* __restrict__ arow, int* __restrict__ counts, int E)
{
    int e = blockIdx.x * 256 + threadIdx.x;
    if (e < E) atomicAdd(&counts[arow[e]], 1);
}

__global__ __launch_bounds__(256) void block_sums(
    const int* __restrict__ counts, int* __restrict__ bsums, int n)
{
    int base = blockIdx.x * 1024 + threadIdx.x * 4;
    int s = 0;
    #pragma unroll
    for (int j = 0; j < 4; j++) { int i = base + j; if (i < n) s += counts[i]; }
    #pragma unroll
    for (int off = 1; off < 64; off <<= 1) s += __shfl_xor(s, off);
    __shared__ int ws[4];
    int lane = threadIdx.x & 63, w = threadIdx.x >> 6;
    if (lane == 0) ws[w] = s;
    __syncthreads();
    if (threadIdx.x == 0) bsums[blockIdx.x] = ws[0] + ws[1] + ws[2] + ws[3];
}

__global__ __launch_bounds__(1024) void scan_bsums(
    int* __restrict__ bsums, int nb, int* __restrict__ offs, int n)
{
    __shared__ int sh[1024];
    int tid = threadIdx.x;
    int v = (tid < nb) ? bsums[tid] : 0;
    sh[tid] = v;
    __syncthreads();
    for (int off = 1; off < 1024; off <<= 1) {
        int t = (tid >= off) ? sh[tid - off] : 0;
        __syncthreads();
        sh[tid] += t;
        __syncthreads();
    }
    if (tid < nb) bsums[tid] = sh[tid] - v;   // exclusive
    if (tid == 0) offs[n] = sh[1023];         // grand total
}

__global__ __launch_bounds__(256) void scan_final(
    const int* __restrict__ counts, const int* __restrict__ bsums,
    int* __restrict__ offs, int* __restrict__ cursor, int n)
{
    int tid  = threadIdx.x;
    int base = blockIdx.x * 1024 + tid * 4;
    int c[4]; int s = 0;
    #pragma unroll
    for (int j = 0; j < 4; j++) { int i = base + j; c[j] = (i < n) ? counts[i] : 0; s += c[j]; }
    int lane = tid & 63, w = tid >> 6;
    int inc = s;
    #pragma unroll
    for (int off = 1; off < 64; off <<= 1) {
        int t = __shfl_up(inc, off);
        if (lane >= off) inc += t;
    }
    __shared__ int ws[4];
    if (lane == 63) ws[w] = inc;
    __syncthreads();
    int woff = 0;
    for (int k = 0; k < w; k++) woff += ws[k];
    int excl = bsums[blockIdx.x] + woff + inc - s;
    #pragma unroll
    for (int j = 0; j < 4; j++) {
        int i = base + j;
        if (i < n) { offs[i] = excl; cursor[i] = excl; }
        excl += c[j];
    }
}

// packed (col, val) records: one 8B store per edge
__global__ __launch_bounds__(256) void scatter_kernel(
    const int* __restrict__ arow, const int* __restrict__ acol,
    const float* __restrict__ aval, int* __restrict__ cursor,
    int2* __restrict__ packed, int E)
{
    int e = blockIdx.x * 256 + threadIdx.x;
    if (e >= E) return;
    int r = arow[e];
    int pos = atomicAdd(&cursor[r], 1);
    packed[pos] = make_int2(acol[e], __float_as_int(aval[e]));
}

// ---------------------------------------------------------------- fused GEMM
// support(bf16) = h @ W ; outb(f32) = h @ W_self + b
__global__ __launch_bounds__(256) void gemm_fused(
    const float* __restrict__ h, const float* __restrict__ W,
    const float* __restrict__ Wself, const float* __restrict__ bias,
    unsigned short* __restrict__ support, float* __restrict__ outb, int N)
{
    __shared__ float Ast[32][32];
    __shared__ float Ws[32][128];
    __shared__ float Wss[32][128];

    const int t  = threadIdx.x;
    const int tx = t & 31;
    const int ty = t >> 5;
    const int r0 = blockIdx.x * 32;

    float acc1[4][4] = {{0.f}};
    float acc2[4][4] = {{0.f}};

    for (int k0 = 0; k0 < DD; k0 += 32) {
        {
            int row = t >> 3;
            int kq  = (t & 7) * 4;
            float4 a = make_float4(0.f, 0.f, 0.f, 0.f);
            int gr = r0 + row;
            if (gr < N) a = *(const float4*)&h[(size_t)gr * DD + k0 + kq];
            Ast[kq + 0][row] = a.x;
            Ast[kq + 1][row] = a.y;
            Ast[kq + 2][row] = a.z;
            Ast[kq + 3][row] = a.w;
        }
        #pragma unroll
        for (int i = 0; i < 4; i++) {
            int idx = t + i * 256;
            int kk  = idx >> 5;
            int cc  = (idx & 31) * 4;
            *(float4*)&Ws[kk][cc]  = *(const float4*)&W[(size_t)(k0 + kk) * DD + cc];
            *(float4*)&Wss[kk][cc] = *(const float4*)&Wself[(size_t)(k0 + kk) * DD + cc];
        }
        __syncthreads();

        #pragma unroll
        for (int k = 0; k < 32; k++) {
            float4 a  = *(float4*)&Ast[k][ty * 4];
            float4 w1 = *(float4*)&Ws[k][tx * 4];
            float4 w2 = *(float4*)&Wss[k][tx * 4];
            float ar[4]  = {a.x, a.y, a.z, a.w};
            float w1r[4] = {w1.x, w1.y, w1.z, w1.w};
            float w2r[4] = {w2.x, w2.y, w2.z, w2.w};
            #pragma unroll
            for (int r = 0; r < 4; r++)
                #pragma unroll
                for (int c = 0; c < 4; c++) {
                    acc1[r][c] += ar[r] * w1r[c];
                    acc2[r][c] += ar[r] * w2r[c];
                }
        }
        __syncthreads();
    }

    const int col0 = tx * 4;
    float4 bv = *(const float4*)&bias[col0];
    #pragma unroll
    for (int r = 0; r < 4; r++) {
        int gr = r0 + ty * 4 + r;
        if (gr < N) {
            ushort4 sb;
            sb.x = f2bf(acc1[r][0]); sb.y = f2bf(acc1[r][1]);
            sb.z = f2bf(acc1[r][2]); sb.w = f2bf(acc1[r][3]);
            *(ushort4*)&support[(size_t)gr * DD + col0] = sb;
            float4 o = make_float4(acc2[r][0] + bv.x, acc2[r][1] + bv.y,
                                   acc2[r][2] + bv.z, acc2[r][3] + bv.w);
            *(float4*)&outb[(size_t)gr * DD + col0] = o;
        }
    }
}

// ---------------------------------------------------------------- SpMM (CSR, bf16 gather)
// 32-thread group per row; unroll 4 edges -> 4 independent gathers in flight
__global__ __launch_bounds__(256) void spmm_csr(
    const int* __restrict__ offs, const int2* __restrict__ packed,
    const unsigned short* __restrict__ sup, float* __restrict__ outb, int N)
{
    const int r   = threadIdx.x & 31;                      // dim quad
    const int row = (blockIdx.x * 256 + threadIdx.x) >> 5;
    if (row >= N) return;

    const int beg = offs[row];
    const int end = offs[row + 1];

    float4 acc = make_float4(0.f, 0.f, 0.f, 0.f);
    int e = beg;
    for (; e + 4 <= end; e += 4) {
        int2 p0 = packed[e + 0];
        int2 p1 = packed[e + 1];
        int2 p2 = packed[e + 2];
        int2 p3 = packed[e + 3];
        ushort4 s0 = *(const ushort4*)&sup[((size_t)p0.x << 7) + r * 4];
        ushort4 s1 = *(const ushort4*)&sup[((size_t)p1.x << 7) + r * 4];
        ushort4 s2 = *(const ushort4*)&sup[((size_t)p2.x << 7) + r * 4];
        ushort4 s3 = *(const ushort4*)&sup[((size_t)p3.x << 7) + r * 4];
        float v0 = __int_as_float(p0.y), v1 = __int_as_float(p1.y);
        float v2 = __int_as_float(p2.y), v3 = __int_as_float(p3.y);
        acc.x += v0 * bf2f(s0.x); acc.y += v0 * bf2f(s0.y);
        acc.z += v0 * bf2f(s0.z); acc.w += v0 * bf2f(s0.w);
        acc.x += v1 * bf2f(s1.x); acc.y += v1 * bf2f(s1.y);
        acc.z += v1 * bf2f(s1.z); acc.w += v1 * bf2f(s1.w);
        acc.x += v2 * bf2f(s2.x); acc.y += v2 * bf2f(s2.y);
        acc.z += v2 * bf2f(s2.z); acc.w += v2 * bf2f(s2.w);
        acc.x += v3 * bf2f(s3.x); acc.y += v3 * bf2f(s3.y);
        acc.z += v3 * bf2f(s3.z); acc.w += v3 * bf2f(s3.w);
    }
    for (; e < end; e++) {
        int2 p = packed[e];
        ushort4 s = *(const ushort4*)&sup[((size_t)p.x << 7) + r * 4];
        float v = __int_as_float(p.y);
        acc.x += v * bf2f(s.x); acc.y += v * bf2f(s.y);
        acc.z += v * bf2f(s.z); acc.w += v * bf2f(s.w);
    }

    float4* op = (float4*)&outb[((size_t)row << 7) + r * 4];
    float4 o = *op;
    o.x += acc.x; o.y += acc.y; o.z += acc.z; o.w += acc.w;
    *op = o;
}

// ---------------------------------------------------------------- BN stats
__global__ __launch_bounds__(256) void bn_stats(
    const float* __restrict__ outb, float* __restrict__ stats, int N)
{
    int c    = threadIdx.x & 127;
    int half = threadIdx.x >> 7;
    float s = 0.f, sq = 0.f;
    for (int r = blockIdx.x * 2 + half; r < N; r += gridDim.x * 2) {
        float v = outb[(size_t)r * DD + c];
        s += v; sq += v * v;
    }
    __shared__ float red[2][2][128];
    red[0][half][c] = s;
    red[1][half][c] = sq;
    __syncthreads();
    if (half == 0) {
        atomicAdd(&stats[c],       red[0][0][c] + red[0][1][c]);
        atomicAdd(&stats[128 + c], red[1][0][c] + red[1][1][c]);
    }
}

// ---------------------------------------------------------------- BN apply + ReLU
// addx==0: hout = relu(bn(outb))
// addx==1: node_emb = relu(bn(outb)) + x; s1/s2 per-row scores vs Wc halves
__global__ __launch_bounds__(256) void bn_apply(
    const float* __restrict__ outb, const float* __restrict__ stats,
    const float* __restrict__ gamma, const float* __restrict__ beta,
    const float* __restrict__ x, float* __restrict__ hout,
    float* __restrict__ s1, float* __restrict__ s2,
    const float* __restrict__ Wc, int N, int addx)
{
    int idx = blockIdx.x * 256 + threadIdx.x;
    int total = N * 32;
    if (idx >= total) return;
    int c4 = (idx & 31) * 4;
    float invN = 1.f / (float)N;
    float4 o = *(const float4*)&outb[(size_t)idx * 4];
    float4 res;
    float* rp = &res.x;
    const float* op = &o.x;
    #pragma unroll
    for (int j = 0; j < 4; j++) {
        int c = c4 + j;
        float mean = stats[c] * invN;
        float var  = stats[128 + c] * invN - mean * mean;
        float sc   = gamma[c] * rsqrtf(var + BN_EPS);
        float sh   = beta[c] - mean * sc;
        float v    = op[j] * sc + sh;
        rp[j] = v > 0.f ? v : 0.f;
    }
    if (!addx) {
        *(float4*)&hout[(size_t)idx * 4] = res;
    } else {
        float4 xv = *(const float4*)&x[(size_t)idx * 4];
        res.x += xv.x; res.y += xv.y; res.z += xv.z; res.w += xv.w;
        float4 w1 = *(const float4*)&Wc[c4];
        float4 w2 = *(const float4*)&Wc[128 + c4];
        float a1 = res.x * w1.x + res.y * w1.y + res.z * w1.z + res.w * w1.w;
        float a2 = res.x * w2.x + res.y * w2.y + res.z * w2.z + res.w * w2.w;
        #pragma unroll
        for (int off = 1; off < 32; off <<= 1) {
            a1 += __shfl_xor(a1, off);
            a2 += __shfl_xor(a2, off);
        }
        if ((idx & 31) == 0) {
            int row = idx >> 5;
            s1[row] = a1;
            s2[row] = a2;
        }
    }
}

// ---------------------------------------------------------------- edge predictor (scalar)
__global__ __launch_bounds__(256) void edge_pred_scalar(
    const float* __restrict__ s1, const float* __restrict__ s2,
    const int* __restrict__ ei, const float* __restrict__ bc,
    float* __restrict__ outp, int Ep)
{
    int e = blockIdx.x * 256 + threadIdx.x;
    if (e >= Ep) return;
    float v = s1[ei[e]] + s2[ei[Ep + e]] + bc[0];
    outp[e] = 1.f / (1.f + expf(-v));
}

// ---------------------------------------------------------------- launch
extern "C" void kernel_launch(void* const* d_in, const int* in_sizes, int n_in,
                              void* d_out, int out_size, void* d_ws, size_t ws_size,
                              hipStream_t stream) {
    const float* x        = (const float*)d_in[0];
    const int*   adj_row  = (const int*)  d_in[1];
    const int*   adj_col  = (const int*)  d_in[2];
    const float* adj_val  = (const float*)d_in[3];
    const int*   ei       = (const int*)  d_in[4];
    const float* W        = (const float*)d_in[5];
    const float* W_self   = (const float*)d_in[6];
    const float* b        = (const float*)d_in[7];
    const float* gamma    = (const float*)d_in[8];
    const float* beta     = (const float*)d_in[9];
    const float* Wc       = (const float*)d_in[10];
    const float* bc       = (const float*)d_in[11];
    float* outp = (float*)d_out;

    const int N  = in_sizes[0] / DD;    // 50000
    const int E  = in_sizes[1];         // 800000
    const int Ep = in_sizes[4] / 2;     // 500000

    size_t nd = (size_t)N * DD;
    unsigned short* support16 = (unsigned short*)d_ws;  // nd bf16 (region sized nd floats)
    float* outb    = (float*)d_ws + nd;
    float* hbuf    = outb + nd;
    float* stats   = hbuf + nd;                 // 512 floats
    int*   counts  = (int*)(stats + 512);       // N
    int*   offs    = counts + N;                // N+2 (padded for 8B alignment below)
    int*   cursor  = offs + N + 2;              // N
    int2*  packed  = (int2*)(cursor + N);       // E records (8B-aligned)
    int*   bsums   = (int*)(packed + E);        // <=1024
    float* s1      = (float*)(bsums + 1024);    // N
    float* s2      = s1 + N;                    // N

    const int nb = (N + 1023) / 1024;

    // ---- build CSR once per call ----
    zero_int_kernel<<<(N + 255) / 256, 256, 0, stream>>>(counts, N);
    zero_int_kernel<<<2, 256, 0, stream>>>((int*)stats, 512);
    hist_kernel<<<(E + 255) / 256, 256, 0, stream>>>(adj_row, counts, E);
    block_sums<<<nb, 256, 0, stream>>>(counts, bsums, N);
    scan_bsums<<<1, 1024, 0, stream>>>(bsums, nb, offs, N);
    scan_final<<<nb, 256, 0, stream>>>(counts, bsums, offs, cursor, N);
    scatter_kernel<<<(E + 255) / 256, 256, 0, stream>>>(
        adj_row, adj_col, adj_val, cursor, packed, E);

    const int gemm_grid = (N + 31) / 32;
    const int spmm_grid = (N * 32 + 255) / 256;   // 32 threads per row
    const int bnap_grid = (N * 32 + 255) / 256;

    for (int i = 0; i < 2; i++) {
        const float* hin = (i == 0) ? x : hbuf;
        gemm_fused<<<gemm_grid, 256, 0, stream>>>(
            hin, W + (size_t)i * DD * DD, W_self + (size_t)i * DD * DD,
            b + (size_t)i * DD, support16, outb, N);
        spmm_csr<<<spmm_grid, 256, 0, stream>>>(
            offs, packed, support16, outb, N);
        bn_stats<<<512, 256, 0, stream>>>(outb, stats + i * 256, N);
        bn_apply<<<bnap_grid, 256, 0, stream>>>(
            outb, stats + i * 256, gamma + (size_t)i * DD, beta + (size_t)i * DD,
            x, hbuf, s1, s2, Wc, N, i == 1 ? 1 : 0);
    }

    edge_pred_scalar<<<(Ep + 255) / 256, 256, 0, stream>>>(s1, s2, ei, bc, outp, Ep);
}

// Round 6
// 409.135 us; speedup vs baseline: 7.3557x; 1.0345x over previous
//
#include <hip/hip_runtime.h>
#include <hip/hip_bf16.h>

#define DD 128
#define BN_EPS 1e-5f

typedef __attribute__((ext_vector_type(8))) short bf16x8;
typedef __attribute__((ext_vector_type(4))) float f32x4;

static __device__ __forceinline__ unsigned short f2bf(float f) {
    __hip_bfloat16 h = __float2bfloat16(f);   // RNE
    return *reinterpret_cast<unsigned short*>(&h);
}
static __device__ __forceinline__ float bf2f(unsigned short u) {
    return __uint_as_float(((unsigned)u) << 16);
}

// ---------------------------------------------------------------- utilities
__global__ __launch_bounds__(256) void zero_int_kernel(int* __restrict__ p, int n) {
    int i = blockIdx.x * 256 + threadIdx.x;
    if (i < n) p[i] = 0;
}

// fp32 -> bf16 (vector4)
__global__ __launch_bounds__(256) void convert_bf16(
    const float* __restrict__ in, unsigned short* __restrict__ out, int n4)
{
    int i = blockIdx.x * 256 + threadIdx.x;
    if (i >= n4) return;
    float4 v = *(const float4*)&in[(size_t)i * 4];
    ushort4 o;
    o.x = f2bf(v.x); o.y = f2bf(v.y); o.z = f2bf(v.z); o.w = f2bf(v.w);
    *(ushort4*)&out[(size_t)i * 4] = o;
}

// transpose + convert the 4 weight matrices: Wt4[mat][n][k] = bf16(src[k][n])
__global__ __launch_bounds__(256) void prep_weights(
    const float* __restrict__ W, const float* __restrict__ Wself,
    unsigned short* __restrict__ Wt4)
{
    int mat = blockIdx.x;        // 0:L0 W, 1:L0 Wself, 2:L1 W, 3:L1 Wself
    int layer = mat >> 1;
    const float* src = (mat & 1) ? (Wself + layer * 16384) : (W + layer * 16384);
    unsigned short* dst = Wt4 + (size_t)mat * 16384;
    for (int i = threadIdx.x; i < 16384; i += 256) {
        int n = i >> 7, k = i & 127;
        dst[i] = f2bf(src[k * 128 + n]);
    }
}

// ---------------------------------------------------------------- CSR build
__global__ __launch_bounds__(256) void hist_kernel(
    const int* __restrict__ arow, int* __restrict__ counts, int E)
{
    int e = blockIdx.x * 256 + threadIdx.x;
    if (e < E) atomicAdd(&counts[arow[e]], 1);
}

__global__ __launch_bounds__(256) void block_sums(
    const int* __restrict__ counts, int* __restrict__ bsums, int n)
{
    int base = blockIdx.x * 1024 + threadIdx.x * 4;
    int s = 0;
    #pragma unroll
    for (int j = 0; j < 4; j++) { int i = base + j; if (i < n) s += counts[i]; }
    #pragma unroll
    for (int off = 1; off < 64; off <<= 1) s += __shfl_xor(s, off);
    __shared__ int ws[4];
    int lane = threadIdx.x & 63, w = threadIdx.x >> 6;
    if (lane == 0) ws[w] = s;
    __syncthreads();
    if (threadIdx.x == 0) bsums[blockIdx.x] = ws[0] + ws[1] + ws[2] + ws[3];
}

__global__ __launch_bounds__(1024) void scan_bsums(
    int* __restrict__ bsums, int nb, int* __restrict__ offs, int n)
{
    __shared__ int sh[1024];
    int tid = threadIdx.x;
    int v = (tid < nb) ? bsums[tid] : 0;
    sh[tid] = v;
    __syncthreads();
    for (int off = 1; off < 1024; off <<= 1) {
        int t = (tid >= off) ? sh[tid - off] : 0;
        __syncthreads();
        sh[tid] += t;
        __syncthreads();
    }
    if (tid < nb) bsums[tid] = sh[tid] - v;   // exclusive
    if (tid == 0) offs[n] = sh[1023];         // grand total
}

__global__ __launch_bounds__(256) void scan_final(
    const int* __restrict__ counts, const int* __restrict__ bsums,
    int* __restrict__ offs, int* __restrict__ cursor, int n)
{
    int tid  = threadIdx.x;
    int base = blockIdx.x * 1024 + tid * 4;
    int c[4]; int s = 0;
    #pragma unroll
    for (int j = 0; j < 4; j++) { int i = base + j; c[j] = (i < n) ? counts[i] : 0; s += c[j]; }
    int lane = tid & 63, w = tid >> 6;
    int inc = s;
    #pragma unroll
    for (int off = 1; off < 64; off <<= 1) {
        int t = __shfl_up(inc, off);
        if (lane >= off) inc += t;
    }
    __shared__ int ws[4];
    if (lane == 63) ws[w] = inc;
    __syncthreads();
    int woff = 0;
    for (int k = 0; k < w; k++) woff += ws[k];
    int excl = bsums[blockIdx.x] + woff + inc - s;
    #pragma unroll
    for (int j = 0; j < 4; j++) {
        int i = base + j;
        if (i < n) { offs[i] = excl; cursor[i] = excl; }
        excl += c[j];
    }
}

__global__ __launch_bounds__(256) void scatter_kernel(
    const int* __restrict__ arow, const int* __restrict__ acol,
    const float* __restrict__ aval, int* __restrict__ cursor,
    int2* __restrict__ packed, int E)
{
    int e = blockIdx.x * 256 + threadIdx.x;
    if (e >= E) return;
    int r = arow[e];
    int pos = atomicAdd(&cursor[r], 1);
    packed[pos] = make_int2(acol[e], __float_as_int(aval[e]));
}

// ---------------------------------------------------------------- MFMA GEMM
// support(bf16) = A @ W ; outb(f32) = A @ W_self + b   (A bf16, K=128)
// block = 256 thr = 4 waves; wave computes 16 rows x 128 cols via 16x16x32 MFMA
__global__ __launch_bounds__(256) void gemm_mfma(
    const unsigned short* __restrict__ Abf,   // [N][128] bf16
    const unsigned short* __restrict__ Wt,    // [128 n][128 k] bf16 (transposed)
    const unsigned short* __restrict__ Wst,   // W_self transposed
    const float* __restrict__ bias,
    unsigned short* __restrict__ support, float* __restrict__ outb, int N)
{
    const int wave = threadIdx.x >> 6;
    const int lane = threadIdx.x & 63;
    const int m    = lane & 15;
    const int quad = lane >> 4;
    const int row0 = blockIdx.x * 64 + wave * 16;

    // A fragments for all 4 K-chunks (A[m][k]: m=lane&15, k=quad*8+j)
    int arow = row0 + m; if (arow > N - 1) arow = N - 1;
    const bf16x8* Ap = (const bf16x8*)(Abf + (size_t)arow * 128 + quad * 8);
    bf16x8 a0 = Ap[0];
    bf16x8 a1 = Ap[4];
    bf16x8 a2 = Ap[8];
    bf16x8 a3 = Ap[12];

    f32x4 acc1[8], acc2[8];
    #pragma unroll
    for (int nt = 0; nt < 8; nt++) {
        acc1[nt] = (f32x4)(0.f);
        acc2[nt] = (f32x4)(0.f);
    }

    #pragma unroll
    for (int nt = 0; nt < 8; nt++) {
        // B[k][n]: n=lane&15 within tile, k=quad*8+j contiguous in Wt[n][k]
        const bf16x8* B1 = (const bf16x8*)(Wt  + ((size_t)(nt * 16 + m)) * 128 + quad * 8);
        const bf16x8* B2 = (const bf16x8*)(Wst + ((size_t)(nt * 16 + m)) * 128 + quad * 8);
        acc1[nt] = __builtin_amdgcn_mfma_f32_16x16x32_bf16(a0, B1[0],  acc1[nt], 0, 0, 0);
        acc2[nt] = __builtin_amdgcn_mfma_f32_16x16x32_bf16(a0, B2[0],  acc2[nt], 0, 0, 0);
        acc1[nt] = __builtin_amdgcn_mfma_f32_16x16x32_bf16(a1, B1[4],  acc1[nt], 0, 0, 0);
        acc2[nt] = __builtin_amdgcn_mfma_f32_16x16x32_bf16(a1, B2[4],  acc2[nt], 0, 0, 0);
        acc1[nt] = __builtin_amdgcn_mfma_f32_16x16x32_bf16(a2, B1[8],  acc1[nt], 0, 0, 0);
        acc2[nt] = __builtin_amdgcn_mfma_f32_16x16x32_bf16(a2, B2[8],  acc2[nt], 0, 0, 0);
        acc1[nt] = __builtin_amdgcn_mfma_f32_16x16x32_bf16(a3, B1[12], acc1[nt], 0, 0, 0);
        acc2[nt] = __builtin_amdgcn_mfma_f32_16x16x32_bf16(a3, B2[12], acc2[nt], 0, 0, 0);
    }

    // bias per lane per n-tile
    float bv[8];
    #pragma unroll
    for (int nt = 0; nt < 8; nt++) bv[nt] = bias[nt * 16 + m];

    // C/D layout: col = lane&15, row = quad*4 + reg
    #pragma unroll
    for (int r = 0; r < 4; r++) {
        int orow = row0 + quad * 4 + r;
        if (orow < N) {
            size_t base = (size_t)orow * 128 + m;
            #pragma unroll
            for (int nt = 0; nt < 8; nt++) {
                support[base + nt * 16] = f2bf(acc1[nt][r]);
                outb[base + nt * 16]    = acc2[nt][r] + bv[nt];
            }
        }
    }
}

// ---------------------------------------------------------------- SpMM (CSR, bf16 gather)
__global__ __launch_bounds__(256) void spmm_csr(
    const int* __restrict__ offs, const int2* __restrict__ packed,
    const unsigned short* __restrict__ sup, float* __restrict__ outb, int N)
{
    const int r   = threadIdx.x & 31;                      // dim quad
    const int row = (blockIdx.x * 256 + threadIdx.x) >> 5;
    if (row >= N) return;

    const int beg = offs[row];
    const int end = offs[row + 1];

    float4 acc = make_float4(0.f, 0.f, 0.f, 0.f);
    int e = beg;
    for (; e + 4 <= end; e += 4) {
        int2 p0 = packed[e + 0];
        int2 p1 = packed[e + 1];
        int2 p2 = packed[e + 2];
        int2 p3 = packed[e + 3];
        ushort4 s0 = *(const ushort4*)&sup[((size_t)p0.x << 7) + r * 4];
        ushort4 s1 = *(const ushort4*)&sup[((size_t)p1.x << 7) + r * 4];
        ushort4 s2 = *(const ushort4*)&sup[((size_t)p2.x << 7) + r * 4];
        ushort4 s3 = *(const ushort4*)&sup[((size_t)p3.x << 7) + r * 4];
        float v0 = __int_as_float(p0.y), v1 = __int_as_float(p1.y);
        float v2 = __int_as_float(p2.y), v3 = __int_as_float(p3.y);
        acc.x += v0 * bf2f(s0.x); acc.y += v0 * bf2f(s0.y);
        acc.z += v0 * bf2f(s0.z); acc.w += v0 * bf2f(s0.w);
        acc.x += v1 * bf2f(s1.x); acc.y += v1 * bf2f(s1.y);
        acc.z += v1 * bf2f(s1.z); acc.w += v1 * bf2f(s1.w);
        acc.x += v2 * bf2f(s2.x); acc.y += v2 * bf2f(s2.y);
        acc.z += v2 * bf2f(s2.z); acc.w += v2 * bf2f(s2.w);
        acc.x += v3 * bf2f(s3.x); acc.y += v3 * bf2f(s3.y);
        acc.z += v3 * bf2f(s3.z); acc.w += v3 * bf2f(s3.w);
    }
    for (; e < end; e++) {
        int2 p = packed[e];
        ushort4 s = *(const ushort4*)&sup[((size_t)p.x << 7) + r * 4];
        float v = __int_as_float(p.y);
        acc.x += v * bf2f(s.x); acc.y += v * bf2f(s.y);
        acc.z += v * bf2f(s.z); acc.w += v * bf2f(s.w);
    }

    float4* op = (float4*)&outb[((size_t)row << 7) + r * 4];
    float4 o = *op;
    o.x += acc.x; o.y += acc.y; o.z += acc.z; o.w += acc.w;
    *op = o;
}

// ---------------------------------------------------------------- BN stats
__global__ __launch_bounds__(256) void bn_stats(
    const float* __restrict__ outb, float* __restrict__ stats, int N)
{
    int c    = threadIdx.x & 127;
    int half = threadIdx.x >> 7;
    float s = 0.f, sq = 0.f;
    for (int r = blockIdx.x * 2 + half; r < N; r += gridDim.x * 2) {
        float v = outb[(size_t)r * DD + c];
        s += v; sq += v * v;
    }
    __shared__ float red[2][2][128];
    red[0][half][c] = s;
    red[1][half][c] = sq;
    __syncthreads();
    if (half == 0) {
        atomicAdd(&stats[c],       red[0][0][c] + red[0][1][c]);
        atomicAdd(&stats[128 + c], red[1][0][c] + red[1][1][c]);
    }
}

// ---------------------------------------------------------------- BN apply + ReLU
// addx==0: hout16 = bf16(relu(bn(outb)))          (layer-1 output, feeds gemm_mfma)
// addx==1: node_emb = relu(bn(outb)) + x; s1/s2 per-row scores vs Wc halves
__global__ __launch_bounds__(256) void bn_apply(
    const float* __restrict__ outb, const float* __restrict__ stats,
    const float* __restrict__ gamma, const float* __restrict__ beta,
    const float* __restrict__ x, unsigned short* __restrict__ hout16,
    float* __restrict__ s1, float* __restrict__ s2,
    const float* __restrict__ Wc, int N, int addx)
{
    int idx = blockIdx.x * 256 + threadIdx.x;
    int total = N * 32;
    if (idx >= total) return;
    int c4 = (idx & 31) * 4;
    float invN = 1.f / (float)N;
    float4 o = *(const float4*)&outb[(size_t)idx * 4];
    float4 res;
    float* rp = &res.x;
    const float* op = &o.x;
    #pragma unroll
    for (int j = 0; j < 4; j++) {
        int c = c4 + j;
        float mean = stats[c] * invN;
        float var  = stats[128 + c] * invN - mean * mean;
        float sc   = gamma[c] * rsqrtf(var + BN_EPS);
        float sh   = beta[c] - mean * sc;
        float v    = op[j] * sc + sh;
        rp[j] = v > 0.f ? v : 0.f;
    }
    if (!addx) {
        ushort4 hb;
        hb.x = f2bf(res.x); hb.y = f2bf(res.y);
        hb.z = f2bf(res.z); hb.w = f2bf(res.w);
        *(ushort4*)&hout16[(size_t)idx * 4] = hb;
    } else {
        float4 xv = *(const float4*)&x[(size_t)idx * 4];
        res.x += xv.x; res.y += xv.y; res.z += xv.z; res.w += xv.w;
        float4 w1 = *(const float4*)&Wc[c4];
        float4 w2 = *(const float4*)&Wc[128 + c4];
        float a1 = res.x * w1.x + res.y * w1.y + res.z * w1.z + res.w * w1.w;
        float a2 = res.x * w2.x + res.y * w2.y + res.z * w2.z + res.w * w2.w;
        #pragma unroll
        for (int off = 1; off < 32; off <<= 1) {
            a1 += __shfl_xor(a1, off);
            a2 += __shfl_xor(a2, off);
        }
        if ((idx & 31) == 0) {
            int row = idx >> 5;
            s1[row] = a1;
            s2[row] = a2;
        }
    }
}

// ---------------------------------------------------------------- edge predictor (scalar)
__global__ __launch_bounds__(256) void edge_pred_scalar(
    const float* __restrict__ s1, const float* __restrict__ s2,
    const int* __restrict__ ei, const float* __restrict__ bc,
    float* __restrict__ outp, int Ep)
{
    int e = blockIdx.x * 256 + threadIdx.x;
    if (e >= Ep) return;
    float v = s1[ei[e]] + s2[ei[Ep + e]] + bc[0];
    outp[e] = 1.f / (1.f + expf(-v));
}

// ---------------------------------------------------------------- launch
extern "C" void kernel_launch(void* const* d_in, const int* in_sizes, int n_in,
                              void* d_out, int out_size, void* d_ws, size_t ws_size,
                              hipStream_t stream) {
    const float* x        = (const float*)d_in[0];
    const int*   adj_row  = (const int*)  d_in[1];
    const int*   adj_col  = (const int*)  d_in[2];
    const float* adj_val  = (const float*)d_in[3];
    const int*   ei       = (const int*)  d_in[4];
    const float* W        = (const float*)d_in[5];
    const float* W_self   = (const float*)d_in[6];
    const float* b        = (const float*)d_in[7];
    const float* gamma    = (const float*)d_in[8];
    const float* beta     = (const float*)d_in[9];
    const float* Wc       = (const float*)d_in[10];
    const float* bc       = (const float*)d_in[11];
    float* outp = (float*)d_out;

    const int N  = in_sizes[0] / DD;    // 50000
    const int E  = in_sizes[1];         // 800000
    const int Ep = in_sizes[4] / 2;     // 500000

    size_t nd = (size_t)N * DD;
    char* p = (char*)d_ws;
    unsigned short* support16 = (unsigned short*)p; p += nd * 2;
    float*          outb      = (float*)p;          p += nd * 4;
    unsigned short* hbf       = (unsigned short*)p; p += nd * 2;
    unsigned short* xbf       = (unsigned short*)p; p += nd * 2;
    unsigned short* Wt4       = (unsigned short*)p; p += 4 * 16384 * 2;
    float*          stats     = (float*)p;          p += 512 * 4;
    int*            counts    = (int*)p;            p += (size_t)N * 4;
    int*            offs      = (int*)p;            p += (size_t)(N + 2) * 4;
    int*            cursor    = (int*)p;            p += (size_t)N * 4;
    int2*           packed    = (int2*)p;           p += (size_t)E * 8;
    int*            bsums     = (int*)p;            p += 1024 * 4;
    float*          s1        = (float*)p;          p += (size_t)N * 4;
    float*          s2        = (float*)p;

    const int nb = (N + 1023) / 1024;

    // ---- prep: bf16 conversions ----
    convert_bf16<<<(int)(nd / 4 + 255) / 256, 256, 0, stream>>>(x, xbf, (int)(nd / 4));
    prep_weights<<<4, 256, 0, stream>>>(W, W_self, Wt4);

    // ---- build CSR once per call ----
    zero_int_kernel<<<(N + 255) / 256, 256, 0, stream>>>(counts, N);
    zero_int_kernel<<<2, 256, 0, stream>>>((int*)stats, 512);
    hist_kernel<<<(E + 255) / 256, 256, 0, stream>>>(adj_row, counts, E);
    block_sums<<<nb, 256, 0, stream>>>(counts, bsums, N);
    scan_bsums<<<1, 1024, 0, stream>>>(bsums, nb, offs, N);
    scan_final<<<nb, 256, 0, stream>>>(counts, bsums, offs, cursor, N);
    scatter_kernel<<<(E + 255) / 256, 256, 0, stream>>>(
        adj_row, adj_col, adj_val, cursor, packed, E);

    const int gemm_grid = (N + 63) / 64;
    const int spmm_grid = (N * 32 + 255) / 256;
    const int bnap_grid = (N * 32 + 255) / 256;

    for (int i = 0; i < 2; i++) {
        const unsigned short* Ain = (i == 0) ? xbf : hbf;
        gemm_mfma<<<gemm_grid, 256, 0, stream>>>(
            Ain, Wt4 + (size_t)(2 * i) * 16384, Wt4 + (size_t)(2 * i + 1) * 16384,
            b + (size_t)i * DD, support16, outb, N);
        spmm_csr<<<spmm_grid, 256, 0, stream>>>(
            offs, packed, support16, outb, N);
        bn_stats<<<512, 256, 0, stream>>>(outb, stats + i * 256, N);
        bn_apply<<<bnap_grid, 256, 0, stream>>>(
            outb, stats + i * 256, gamma + (size_t)i * DD, beta + (size_t)i * DD,
            x, hbf, s1, s2, Wc, N, i == 1 ? 1 : 0);
    }

    edge_pred_scalar<<<(Ep + 255) / 256, 256, 0, stream>>>(s1, s2, ei, bc, outp, Ep);
}

// Round 7
// 405.510 us; speedup vs baseline: 7.4215x; 1.0089x over previous
//
#include <hip/hip_runtime.h>
#include <hip/hip_bf16.h>
#include <hip/hip_fp16.h>

#define DD 128
#define BN_EPS 1e-5f

typedef __attribute__((ext_vector_type(8))) short bf16x8;
typedef __attribute__((ext_vector_type(4))) float f32x4;

static __device__ __forceinline__ unsigned short f2bf(float f) {
    __hip_bfloat16 h = __float2bfloat16(f);   // RNE
    return *reinterpret_cast<unsigned short*>(&h);
}
static __device__ __forceinline__ float bf2f(unsigned short u) {
    return __uint_as_float(((unsigned)u) << 16);
}
static __device__ __forceinline__ unsigned pack_rec(int col, float val) {
    __half h = __float2half(val);
    unsigned hb = *reinterpret_cast<unsigned short*>(&h);
    return (unsigned)col | (hb << 16);
}
static __device__ __forceinline__ float rec_val(unsigned rec) {
    unsigned short hb = (unsigned short)(rec >> 16);
    __half h = *reinterpret_cast<__half*>(&hb);
    return __half2float(h);
}

// ---------------------------------------------------------------- utilities
__global__ __launch_bounds__(256) void zero_int_kernel(int* __restrict__ p, int n) {
    int i = blockIdx.x * 256 + threadIdx.x;
    if (i < n) p[i] = 0;
}

// fp32 -> bf16 (vector4)
__global__ __launch_bounds__(256) void convert_bf16(
    const float* __restrict__ in, unsigned short* __restrict__ out, int n4)
{
    int i = blockIdx.x * 256 + threadIdx.x;
    if (i >= n4) return;
    float4 v = *(const float4*)&in[(size_t)i * 4];
    ushort4 o;
    o.x = f2bf(v.x); o.y = f2bf(v.y); o.z = f2bf(v.z); o.w = f2bf(v.w);
    *(ushort4*)&out[(size_t)i * 4] = o;
}

// transpose + convert the 4 weight matrices: Wt4[mat][n][k] = bf16(src[k][n])
__global__ __launch_bounds__(256) void prep_weights(
    const float* __restrict__ W, const float* __restrict__ Wself,
    unsigned short* __restrict__ Wt4)
{
    int mat = blockIdx.x;        // 0:L0 W, 1:L0 Wself, 2:L1 W, 3:L1 Wself
    int layer = mat >> 1;
    const float* src = (mat & 1) ? (Wself + layer * 16384) : (W + layer * 16384);
    unsigned short* dst = Wt4 + (size_t)mat * 16384;
    for (int i = threadIdx.x; i < 16384; i += 256) {
        int n = i >> 7, k = i & 127;
        dst[i] = f2bf(src[k * 128 + n]);
    }
}

// ---------------------------------------------------------------- CSR build
__global__ __launch_bounds__(256) void hist_kernel(
    const int* __restrict__ arow, int* __restrict__ counts, int E)
{
    int e = blockIdx.x * 256 + threadIdx.x;
    if (e < E) atomicAdd(&counts[arow[e]], 1);
}

__global__ __launch_bounds__(256) void block_sums(
    const int* __restrict__ counts, int* __restrict__ bsums, int n)
{
    int base = blockIdx.x * 1024 + threadIdx.x * 4;
    int s = 0;
    #pragma unroll
    for (int j = 0; j < 4; j++) { int i = base + j; if (i < n) s += counts[i]; }
    #pragma unroll
    for (int off = 1; off < 64; off <<= 1) s += __shfl_xor(s, off);
    __shared__ int ws[4];
    int lane = threadIdx.x & 63, w = threadIdx.x >> 6;
    if (lane == 0) ws[w] = s;
    __syncthreads();
    if (threadIdx.x == 0) bsums[blockIdx.x] = ws[0] + ws[1] + ws[2] + ws[3];
}

__global__ __launch_bounds__(1024) void scan_bsums(
    int* __restrict__ bsums, int nb, int* __restrict__ offs, int n)
{
    __shared__ int sh[1024];
    int tid = threadIdx.x;
    int v = (tid < nb) ? bsums[tid] : 0;
    sh[tid] = v;
    __syncthreads();
    for (int off = 1; off < 1024; off <<= 1) {
        int t = (tid >= off) ? sh[tid - off] : 0;
        __syncthreads();
        sh[tid] += t;
        __syncthreads();
    }
    if (tid < nb) bsums[tid] = sh[tid] - v;   // exclusive
    if (tid == 0) offs[n] = sh[1023];         // grand total
}

__global__ __launch_bounds__(256) void scan_final(
    const int* __restrict__ counts, const int* __restrict__ bsums,
    int* __restrict__ offs, int* __restrict__ cursor, int n)
{
    int tid  = threadIdx.x;
    int base = blockIdx.x * 1024 + tid * 4;
    int c[4]; int s = 0;
    #pragma unroll
    for (int j = 0; j < 4; j++) { int i = base + j; c[j] = (i < n) ? counts[i] : 0; s += c[j]; }
    int lane = tid & 63, w = tid >> 6;
    int inc = s;
    #pragma unroll
    for (int off = 1; off < 64; off <<= 1) {
        int t = __shfl_up(inc, off);
        if (lane >= off) inc += t;
    }
    __shared__ int ws[4];
    if (lane == 63) ws[w] = inc;
    __syncthreads();
    int woff = 0;
    for (int k = 0; k < w; k++) woff += ws[k];
    int excl = bsums[blockIdx.x] + woff + inc - s;
    #pragma unroll
    for (int j = 0; j < 4; j++) {
        int i = base + j;
        if (i < n) { offs[i] = excl; cursor[i] = excl; }
        excl += c[j];
    }
}

// XCD-partitioned scatter: workgroup (slice = blockIdx>>3, p = blockIdx&7)
// writes only rows in partition p -> each contiguous CSR region is written
// (heuristically) by one XCD => no cross-XCD line ping-pong.
__global__ __launch_bounds__(256) void scatter_part(
    const int* __restrict__ arow, const int* __restrict__ acol,
    const float* __restrict__ aval, int* __restrict__ cursor,
    unsigned* __restrict__ packed, int E, int rpp /* rows per partition */)
{
    const int p      = blockIdx.x & 7;
    const int slice  = blockIdx.x >> 3;
    const int nsl    = gridDim.x >> 3;
    const int e0     = (int)((long long)E * slice / nsl);
    const int e1     = (int)((long long)E * (slice + 1) / nsl);
    for (int e = e0 + threadIdx.x; e < e1; e += 256) {
        int r = arow[e];
        if (r / rpp == p) {
            int pos = atomicAdd(&cursor[r], 1);
            packed[pos] = pack_rec(acol[e], aval[e]);
        }
    }
}

// ---------------------------------------------------------------- MFMA GEMM
// support(bf16) = A @ W ; outb(f32) = A @ W_self + b   (A bf16, K=128)
__global__ __launch_bounds__(256) void gemm_mfma(
    const unsigned short* __restrict__ Abf,   // [N][128] bf16
    const unsigned short* __restrict__ Wt,    // [128 n][128 k] bf16 (transposed)
    const unsigned short* __restrict__ Wst,   // W_self transposed
    const float* __restrict__ bias,
    unsigned short* __restrict__ support, float* __restrict__ outb, int N)
{
    const int wave = threadIdx.x >> 6;
    const int lane = threadIdx.x & 63;
    const int m    = lane & 15;
    const int quad = lane >> 4;
    const int row0 = blockIdx.x * 64 + wave * 16;

    int arow = row0 + m; if (arow > N - 1) arow = N - 1;
    const bf16x8* Ap = (const bf16x8*)(Abf + (size_t)arow * 128 + quad * 8);
    bf16x8 a0 = Ap[0];
    bf16x8 a1 = Ap[4];
    bf16x8 a2 = Ap[8];
    bf16x8 a3 = Ap[12];

    f32x4 acc1[8], acc2[8];
    #pragma unroll
    for (int nt = 0; nt < 8; nt++) {
        acc1[nt] = (f32x4)(0.f);
        acc2[nt] = (f32x4)(0.f);
    }

    #pragma unroll
    for (int nt = 0; nt < 8; nt++) {
        const bf16x8* B1 = (const bf16x8*)(Wt  + ((size_t)(nt * 16 + m)) * 128 + quad * 8);
        const bf16x8* B2 = (const bf16x8*)(Wst + ((size_t)(nt * 16 + m)) * 128 + quad * 8);
        acc1[nt] = __builtin_amdgcn_mfma_f32_16x16x32_bf16(a0, B1[0],  acc1[nt], 0, 0, 0);
        acc2[nt] = __builtin_amdgcn_mfma_f32_16x16x32_bf16(a0, B2[0],  acc2[nt], 0, 0, 0);
        acc1[nt] = __builtin_amdgcn_mfma_f32_16x16x32_bf16(a1, B1[4],  acc1[nt], 0, 0, 0);
        acc2[nt] = __builtin_amdgcn_mfma_f32_16x16x32_bf16(a1, B2[4],  acc2[nt], 0, 0, 0);
        acc1[nt] = __builtin_amdgcn_mfma_f32_16x16x32_bf16(a2, B1[8],  acc1[nt], 0, 0, 0);
        acc2[nt] = __builtin_amdgcn_mfma_f32_16x16x32_bf16(a2, B2[8],  acc2[nt], 0, 0, 0);
        acc1[nt] = __builtin_amdgcn_mfma_f32_16x16x32_bf16(a3, B1[12], acc1[nt], 0, 0, 0);
        acc2[nt] = __builtin_amdgcn_mfma_f32_16x16x32_bf16(a3, B2[12], acc2[nt], 0, 0, 0);
    }

    float bv[8];
    #pragma unroll
    for (int nt = 0; nt < 8; nt++) bv[nt] = bias[nt * 16 + m];

    // C/D layout: col = lane&15, row = quad*4 + reg
    #pragma unroll
    for (int r = 0; r < 4; r++) {
        int orow = row0 + quad * 4 + r;
        if (orow < N) {
            size_t base = (size_t)orow * 128 + m;
            #pragma unroll
            for (int nt = 0; nt < 8; nt++) {
                support[base + nt * 16] = f2bf(acc1[nt][r]);
                outb[base + nt * 16]    = acc2[nt][r] + bv[nt];
            }
        }
    }
}

// ---------------------------------------------------------------- SpMM (CSR, bf16 gather)
__global__ __launch_bounds__(256) void spmm_csr(
    const int* __restrict__ offs, const unsigned* __restrict__ packed,
    const unsigned short* __restrict__ sup, float* __restrict__ outb, int N)
{
    const int r   = threadIdx.x & 31;                      // dim quad
    const int row = (blockIdx.x * 256 + threadIdx.x) >> 5;
    if (row >= N) return;

    const int beg = offs[row];
    const int end = offs[row + 1];

    float4 acc = make_float4(0.f, 0.f, 0.f, 0.f);
    int e = beg;
    for (; e + 4 <= end; e += 4) {
        unsigned p0 = packed[e + 0];
        unsigned p1 = packed[e + 1];
        unsigned p2 = packed[e + 2];
        unsigned p3 = packed[e + 3];
        ushort4 s0 = *(const ushort4*)&sup[((size_t)(p0 & 0xFFFF) << 7) + r * 4];
        ushort4 s1 = *(const ushort4*)&sup[((size_t)(p1 & 0xFFFF) << 7) + r * 4];
        ushort4 s2 = *(const ushort4*)&sup[((size_t)(p2 & 0xFFFF) << 7) + r * 4];
        ushort4 s3 = *(const ushort4*)&sup[((size_t)(p3 & 0xFFFF) << 7) + r * 4];
        float v0 = rec_val(p0), v1 = rec_val(p1);
        float v2 = rec_val(p2), v3 = rec_val(p3);
        acc.x += v0 * bf2f(s0.x); acc.y += v0 * bf2f(s0.y);
        acc.z += v0 * bf2f(s0.z); acc.w += v0 * bf2f(s0.w);
        acc.x += v1 * bf2f(s1.x); acc.y += v1 * bf2f(s1.y);
        acc.z += v1 * bf2f(s1.z); acc.w += v1 * bf2f(s1.w);
        acc.x += v2 * bf2f(s2.x); acc.y += v2 * bf2f(s2.y);
        acc.z += v2 * bf2f(s2.z); acc.w += v2 * bf2f(s2.w);
        acc.x += v3 * bf2f(s3.x); acc.y += v3 * bf2f(s3.y);
        acc.z += v3 * bf2f(s3.z); acc.w += v3 * bf2f(s3.w);
    }
    for (; e < end; e++) {
        unsigned pr = packed[e];
        ushort4 s = *(const ushort4*)&sup[((size_t)(pr & 0xFFFF) << 7) + r * 4];
        float v = rec_val(pr);
        acc.x += v * bf2f(s.x); acc.y += v * bf2f(s.y);
        acc.z += v * bf2f(s.z); acc.w += v * bf2f(s.w);
    }

    float4* op = (float4*)&outb[((size_t)row << 7) + r * 4];
    float4 o = *op;
    o.x += acc.x; o.y += acc.y; o.z += acc.z; o.w += acc.w;
    *op = o;
}

// ---------------------------------------------------------------- BN stats
__global__ __launch_bounds__(256) void bn_stats(
    const float* __restrict__ outb, float* __restrict__ stats, int N)
{
    int c    = threadIdx.x & 127;
    int half = threadIdx.x >> 7;
    float s = 0.f, sq = 0.f;
    for (int r = blockIdx.x * 2 + half; r < N; r += gridDim.x * 2) {
        float v = outb[(size_t)r * DD + c];
        s += v; sq += v * v;
    }
    __shared__ float red[2][2][128];
    red[0][half][c] = s;
    red[1][half][c] = sq;
    __syncthreads();
    if (half == 0) {
        atomicAdd(&stats[c],       red[0][0][c] + red[0][1][c]);
        atomicAdd(&stats[128 + c], red[1][0][c] + red[1][1][c]);
    }
}

// ---------------------------------------------------------------- BN apply + ReLU
__global__ __launch_bounds__(256) void bn_apply(
    const float* __restrict__ outb, const float* __restrict__ stats,
    const float* __restrict__ gamma, const float* __restrict__ beta,
    const float* __restrict__ x, unsigned short* __restrict__ hout16,
    float* __restrict__ s1, float* __restrict__ s2,
    const float* __restrict__ Wc, int N, int addx)
{
    int idx = blockIdx.x * 256 + threadIdx.x;
    int total = N * 32;
    if (idx >= total) return;
    int c4 = (idx & 31) * 4;
    float invN = 1.f / (float)N;
    float4 o = *(const float4*)&outb[(size_t)idx * 4];
    float4 res;
    float* rp = &res.x;
    const float* op = &o.x;
    #pragma unroll
    for (int j = 0; j < 4; j++) {
        int c = c4 + j;
        float mean = stats[c] * invN;
        float var  = stats[128 + c] * invN - mean * mean;
        float sc   = gamma[c] * rsqrtf(var + BN_EPS);
        float sh   = beta[c] - mean * sc;
        float v    = op[j] * sc + sh;
        rp[j] = v > 0.f ? v : 0.f;
    }
    if (!addx) {
        ushort4 hb;
        hb.x = f2bf(res.x); hb.y = f2bf(res.y);
        hb.z = f2bf(res.z); hb.w = f2bf(res.w);
        *(ushort4*)&hout16[(size_t)idx * 4] = hb;
    } else {
        float4 xv = *(const float4*)&x[(size_t)idx * 4];
        res.x += xv.x; res.y += xv.y; res.z += xv.z; res.w += xv.w;
        float4 w1 = *(const float4*)&Wc[c4];
        float4 w2 = *(const float4*)&Wc[128 + c4];
        float a1 = res.x * w1.x + res.y * w1.y + res.z * w1.z + res.w * w1.w;
        float a2 = res.x * w2.x + res.y * w2.y + res.z * w2.z + res.w * w2.w;
        #pragma unroll
        for (int off = 1; off < 32; off <<= 1) {
            a1 += __shfl_xor(a1, off);
            a2 += __shfl_xor(a2, off);
        }
        if ((idx & 31) == 0) {
            int row = idx >> 5;
            s1[row] = a1;
            s2[row] = a2;
        }
    }
}

// ---------------------------------------------------------------- edge predictor (scalar)
__global__ __launch_bounds__(256) void edge_pred_scalar(
    const float* __restrict__ s1, const float* __restrict__ s2,
    const int* __restrict__ ei, const float* __restrict__ bc,
    float* __restrict__ outp, int Ep)
{
    int e = blockIdx.x * 256 + threadIdx.x;
    if (e >= Ep) return;
    float v = s1[ei[e]] + s2[ei[Ep + e]] + bc[0];
    outp[e] = 1.f / (1.f + expf(-v));
}

// ---------------------------------------------------------------- launch
extern "C" void kernel_launch(void* const* d_in, const int* in_sizes, int n_in,
                              void* d_out, int out_size, void* d_ws, size_t ws_size,
                              hipStream_t stream) {
    const float* x        = (const float*)d_in[0];
    const int*   adj_row  = (const int*)  d_in[1];
    const int*   adj_col  = (const int*)  d_in[2];
    const float* adj_val  = (const float*)d_in[3];
    const int*   ei       = (const int*)  d_in[4];
    const float* W        = (const float*)d_in[5];
    const float* W_self   = (const float*)d_in[6];
    const float* b        = (const float*)d_in[7];
    const float* gamma    = (const float*)d_in[8];
    const float* beta     = (const float*)d_in[9];
    const float* Wc       = (const float*)d_in[10];
    const float* bc       = (const float*)d_in[11];
    float* outp = (float*)d_out;

    const int N  = in_sizes[0] / DD;    // 50000
    const int E  = in_sizes[1];         // 800000
    const int Ep = in_sizes[4] / 2;     // 500000

    size_t nd = (size_t)N * DD;
    char* p = (char*)d_ws;
    unsigned short* support16 = (unsigned short*)p; p += nd * 2;
    float*          outb      = (float*)p;          p += nd * 4;
    unsigned short* hbf       = (unsigned short*)p; p += nd * 2;
    unsigned short* xbf       = (unsigned short*)p; p += nd * 2;
    unsigned short* Wt4       = (unsigned short*)p; p += 4 * 16384 * 2;
    float*          stats     = (float*)p;          p += 512 * 4;
    int*            counts    = (int*)p;            p += (size_t)N * 4;
    int*            offs      = (int*)p;            p += (size_t)(N + 2) * 4;
    int*            cursor    = (int*)p;            p += (size_t)N * 4;
    unsigned*       packed    = (unsigned*)p;       p += (size_t)E * 4;
    int*            bsums     = (int*)p;            p += 1024 * 4;
    float*          s1        = (float*)p;          p += (size_t)N * 4;
    float*          s2        = (float*)p;

    const int nb  = (N + 1023) / 1024;
    const int rpp = (N + 7) / 8;        // rows per partition

    // ---- prep: bf16 conversions ----
    convert_bf16<<<(int)(nd / 4 + 255) / 256, 256, 0, stream>>>(x, xbf, (int)(nd / 4));
    prep_weights<<<4, 256, 0, stream>>>(W, W_self, Wt4);

    // ---- build CSR once per call ----
    zero_int_kernel<<<(N + 255) / 256, 256, 0, stream>>>(counts, N);
    zero_int_kernel<<<2, 256, 0, stream>>>((int*)stats, 512);
    hist_kernel<<<(E + 255) / 256, 256, 0, stream>>>(adj_row, counts, E);
    block_sums<<<nb, 256, 0, stream>>>(counts, bsums, N);
    scan_bsums<<<1, 1024, 0, stream>>>(bsums, nb, offs, N);
    scan_final<<<nb, 256, 0, stream>>>(counts, bsums, offs, cursor, N);
    scatter_part<<<256 * 8, 256, 0, stream>>>(
        adj_row, adj_col, adj_val, cursor, packed, E, rpp);

    const int gemm_grid = (N + 63) / 64;
    const int spmm_grid = (N * 32 + 255) / 256;
    const int bnap_grid = (N * 32 + 255) / 256;

    for (int i = 0; i < 2; i++) {
        const unsigned short* Ain = (i == 0) ? xbf : hbf;
        gemm_mfma<<<gemm_grid, 256, 0, stream>>>(
            Ain, Wt4 + (size_t)(2 * i) * 16384, Wt4 + (size_t)(2 * i + 1) * 16384,
            b + (size_t)i * DD, support16, outb, N);
        spmm_csr<<<spmm_grid, 256, 0, stream>>>(
            offs, packed, support16, outb, N);
        bn_stats<<<512, 256, 0, stream>>>(outb, stats + i * 256, N);
        bn_apply<<<bnap_grid, 256, 0, stream>>>(
            outb, stats + i * 256, gamma + (size_t)i * DD, beta + (size_t)i * DD,
            x, hbf, s1, s2, Wc, N, i == 1 ? 1 : 0);
    }

    edge_pred_scalar<<<(Ep + 255) / 256, 256, 0, stream>>>(s1, s2, ei, bc, outp, Ep);
}